// Round 1
// 926.930 us; speedup vs baseline: 1.2038x; 1.2038x over previous
//
#include <hip/hip_runtime.h>
#include <cmath>

typedef __bf16 bf16_t;
typedef __bf16 bf16x8 __attribute__((ext_vector_type(8)));
typedef __bf16 bf16x4 __attribute__((ext_vector_type(4)));
typedef float  f32x4  __attribute__((ext_vector_type(4)));

#define SLEN 2048
#define DMOD 2048
#define NHQ  32
#define NHKV 4
#define HD   128
#define NQC  4096
#define NKVC 512
#define NQKVC 5120
#define NEXP 8
#define NF   768

// LDS strides for attention tiles (see round-4 note: inner dim >= full tile
// extent, stride % 8 == 0 for aligned ds_read_b128).
#define KSTR 136
#define VSTR 72
#define PSTR 72

// ---------------- helpers ----------------
__device__ __forceinline__ float wredsum(float v) {
#pragma unroll
  for (int off = 32; off > 0; off >>= 1) v += __shfl_xor(v, off);
  return v;
}

// async global->LDS, 16 B per lane. LDS dest is wave-uniform base + lane*16
// (HW rule) -> pass a wave-uniform LDS pointer; per-lane global pointers.
__device__ __forceinline__ void gll16(const bf16_t* g, bf16_t* l) {
  __builtin_amdgcn_global_load_lds((const __attribute__((address_space(1))) void*)g,
                                   (__attribute__((address_space(3))) void*)l, 16, 0, 0);
}

// ---------------- rope table (fp64 for accuracy) ----------------
__global__ void rope_table_k(float* __restrict__ cosT, float* __restrict__ sinT) {
  int idx = blockIdx.x * 256 + threadIdx.x;
  if (idx >= SLEN * 64) return;
  int t = idx >> 6, j = idx & 63;
  double inv = exp(-0.2158673524681918 * (double)j);  // ln(1e6)/64
  double ang = (double)t * inv;
  cosT[idx] = (float)cos(ang);
  sinT[idx] = (float)sin(ang);
}

// ---------------- weight transpose: fp32 [R][C] -> bf16 hi/lo pair [C][R] ----------------
__global__ __launch_bounds__(256) void transpose_split2_k(const float* __restrict__ in,
                                                          bf16_t* __restrict__ outH,
                                                          bf16_t* __restrict__ outL,
                                                          int R, int C) {
  __shared__ float tile[32][33];
  int tx = threadIdx.x, ty = threadIdx.y;
  int c0 = blockIdx.x * 32, r0 = blockIdx.y * 32;
#pragma unroll
  for (int i = 0; i < 4; i++)
    tile[ty + i * 8][tx] = in[(size_t)(r0 + ty + i * 8) * C + c0 + tx];
  __syncthreads();
#pragma unroll
  for (int i = 0; i < 4; i++) {
    int c = c0 + ty + i * 8;
    int r = r0 + tx;
    float w = tile[tx][ty + i * 8];
    bf16_t hi = (bf16_t)w;
    bf16_t lo = (bf16_t)(w - (float)hi);
    size_t o = (size_t)c * R + r;
    outH[o] = hi;
    outL[o] = lo;
  }
}

// ---------------- plain transpose: fp32 [b][R][C] -> bf16 [b][C][R] ----------------
__global__ __launch_bounds__(256) void transpose_plain_k(const float* __restrict__ in,
                                                         bf16_t* __restrict__ out,
                                                         int R, int C) {
  __shared__ float tile[32][33];
  int b = blockIdx.z;
  const float* inb = in + (size_t)b * R * C;
  bf16_t* outb = out + (size_t)b * R * C;
  int tx = threadIdx.x, ty = threadIdx.y;
  int c0 = blockIdx.x * 32, r0 = blockIdx.y * 32;
#pragma unroll
  for (int i = 0; i < 4; i++)
    tile[ty + i * 8][tx] = inb[(size_t)(r0 + ty + i * 8) * C + c0 + tx];
  __syncthreads();
#pragma unroll
  for (int i = 0; i < 4; i++) {
    int c = c0 + ty + i * 8;
    int r = r0 + tx;
    outb[(size_t)c * R + r] = (bf16_t)tile[tx][ty + i * 8];
  }
}

// ---------------- rmsnorm1: fp32 row -> bf16 hi/lo pair [t][2048] ----------------
__global__ __launch_bounds__(256) void rmsnorm1_k(const float* __restrict__ hs,
                                                  const float* __restrict__ sc,
                                                  bf16_t* __restrict__ xnH,
                                                  bf16_t* __restrict__ xnL) {
  const int t = blockIdx.x;
  const float* row = hs + (size_t)t * DMOD;
  const int tid = threadIdx.x;
  const int i0 = tid * 8;
  float4 a = *(const float4*)(row + i0);
  float4 b = *(const float4*)(row + i0 + 4);
  float x[8] = {a.x, a.y, a.z, a.w, b.x, b.y, b.z, b.w};
  float ss = 0.f;
#pragma unroll
  for (int j = 0; j < 8; j++) ss += x[j] * x[j];
  ss = wredsum(ss);
  __shared__ float red[4];
  if ((tid & 63) == 0) red[tid >> 6] = ss;
  __syncthreads();
  float rn = rsqrtf((red[0] + red[1] + red[2] + red[3]) * (1.f / 2048.f) + 1e-6f);
#pragma unroll
  for (int j = 0; j < 8; j++) {
    float v = x[j] * rn * sc[i0 + j];
    bf16_t hi = (bf16_t)v;
    bf16_t lo = (bf16_t)(v - (float)hi);
    xnH[(size_t)t * DMOD + i0 + j] = hi;
    xnL[(size_t)t * DMOD + i0 + j] = lo;
  }
}

// ---------------- 128x128 split MFMA GEMM (m97 structure + hi/lo split) ----------------
// 4 waves in 2x2; each wave owns a 64x64 quadrant = 4x4 MFMA tiles.
// Staging via global_load_lds width=16, tiles [128][32] bf16, NO padding
// (global_load_lds dest = wave-uniform base + lane*16; mapping verified:
//  t=w*64+l -> row=issue*64+(t>>2), col=(t&3)*8  <=>  byte off issue*4096+w*1024+l*16).
template <bool RESID>
__global__ __launch_bounds__(256) void gemm_split128_k(const bf16_t* __restrict__ Ah,
                                                       const bf16_t* __restrict__ Al,
                                                       int lda,
                                                       const bf16_t* __restrict__ Bh,
                                                       const bf16_t* __restrict__ Bl,
                                                       int ldb, int K,
                                                       const float* __restrict__ resid,
                                                       float* __restrict__ C, int ldc) {
  __shared__ bf16_t AsH[128][32], AsL[128][32], BsH[128][32], BsL[128][32];
  const int t = threadIdx.x;
  const int w = t >> 6, lane = t & 63;
  const int m16 = lane & 15, quad = lane >> 4;
  const int m0 = blockIdx.y * 128, n0 = blockIdx.x * 128;
  const int wm = (w & 1) * 64, wn = (w >> 1) * 64;
  f32x4 acc[4][4];
#pragma unroll
  for (int i = 0; i < 4; i++)
#pragma unroll
    for (int j = 0; j < 4; j++) acc[i][j] = (f32x4){0.f, 0.f, 0.f, 0.f};

  const int srow = t >> 2;         // 0..63
  const int scol = (t & 3) * 8;    // element col within BK=32
  const int lw = w * 512;          // wave-uniform LDS elem offset
  const bf16_t* gAh0 = Ah + (size_t)(m0 + srow) * lda + scol;
  const bf16_t* gAh1 = Ah + (size_t)(m0 + 64 + srow) * lda + scol;
  const bf16_t* gAl0 = Al + (size_t)(m0 + srow) * lda + scol;
  const bf16_t* gAl1 = Al + (size_t)(m0 + 64 + srow) * lda + scol;
  const bf16_t* gBh0 = Bh + (size_t)(n0 + srow) * ldb + scol;
  const bf16_t* gBh1 = Bh + (size_t)(n0 + 64 + srow) * ldb + scol;
  const bf16_t* gBl0 = Bl + (size_t)(n0 + srow) * ldb + scol;
  const bf16_t* gBl1 = Bl + (size_t)(n0 + 64 + srow) * ldb + scol;

  for (int k0 = 0; k0 < K; k0 += 32) {
    __syncthreads();
    gll16(gAh0 + k0, &AsH[0][0] + lw);
    gll16(gAh1 + k0, &AsH[0][0] + 2048 + lw);
    gll16(gAl0 + k0, &AsL[0][0] + lw);
    gll16(gAl1 + k0, &AsL[0][0] + 2048 + lw);
    gll16(gBh0 + k0, &BsH[0][0] + lw);
    gll16(gBh1 + k0, &BsH[0][0] + 2048 + lw);
    gll16(gBl0 + k0, &BsL[0][0] + lw);
    gll16(gBl1 + k0, &BsL[0][0] + 2048 + lw);
    __syncthreads();
    bf16x8 a_h[4], a_l[4];
#pragma unroll
    for (int mt = 0; mt < 4; mt++) {
      a_h[mt] = *(const bf16x8*)(&AsH[wm + mt * 16 + m16][quad * 8]);
      a_l[mt] = *(const bf16x8*)(&AsL[wm + mt * 16 + m16][quad * 8]);
    }
#pragma unroll
    for (int nt = 0; nt < 4; nt++) {
      bf16x8 b_h = *(const bf16x8*)(&BsH[wn + nt * 16 + m16][quad * 8]);
      bf16x8 b_l = *(const bf16x8*)(&BsL[wn + nt * 16 + m16][quad * 8]);
#pragma unroll
      for (int mt = 0; mt < 4; mt++) {
        acc[mt][nt] = __builtin_amdgcn_mfma_f32_16x16x32_bf16(a_h[mt], b_h, acc[mt][nt], 0, 0, 0);
        acc[mt][nt] = __builtin_amdgcn_mfma_f32_16x16x32_bf16(a_l[mt], b_h, acc[mt][nt], 0, 0, 0);
        acc[mt][nt] = __builtin_amdgcn_mfma_f32_16x16x32_bf16(a_h[mt], b_l, acc[mt][nt], 0, 0, 0);
      }
    }
  }
  // epilogue: C row = m0+wm+mt*16+quad*4+r, col = n0+wn+nt*16+m16
#pragma unroll
  for (int mt = 0; mt < 4; mt++)
#pragma unroll
    for (int r = 0; r < 4; r++) {
      const size_t row = m0 + wm + mt * 16 + quad * 4 + r;
#pragma unroll
      for (int nt = 0; nt < 4; nt++) {
        const size_t idx = row * ldc + n0 + wn + nt * 16 + m16;
        if (RESID) C[idx] = acc[mt][nt][r] + resid[idx];
        else       C[idx] = acc[mt][nt][r];
      }
    }
}

// ---------------- plain MFMA GEMM core (MoE, bf16 single) ----------------
template <class AROW>
__device__ __forceinline__ void gemm_core(AROW getA, const bf16_t* __restrict__ Bt, int ldb,
                                          int n0, int K, f32x4 acc[4]) {
  __shared__ bf16_t As[64][32];
  __shared__ bf16_t Bs[64][32];
  const int t = threadIdx.x;
  const int wave = t >> 6, lane = t & 63;
  const int m16 = lane & 15, quad = lane >> 4;
  const int sr = t >> 2, sc = (t & 3) << 3;
  const bf16_t* __restrict__ arow = getA(sr);
  const bf16_t* __restrict__ brow = Bt + (size_t)(n0 + sr) * ldb;
  for (int k0 = 0; k0 < K; k0 += 32) {
    __syncthreads();
    *(uint4*)(&As[sr][sc]) = *(const uint4*)(arow + k0 + sc);
    *(uint4*)(&Bs[sr][sc]) = *(const uint4*)(brow + k0 + sc);
    __syncthreads();
    bf16x8 af = *(const bf16x8*)(&As[wave * 16 + m16][quad * 8]);
#pragma unroll
    for (int nt = 0; nt < 4; nt++) {
      bf16x8 bfr = *(const bf16x8*)(&Bs[nt * 16 + m16][quad * 8]);
      acc[nt] = __builtin_amdgcn_mfma_f32_16x16x32_bf16(af, bfr, acc[nt], 0, 0, 0);
    }
  }
}

// ---------------- qk-norm + rope, IN-PLACE on fp32 qkv ----------------
__global__ __launch_bounds__(128) void qknorm_rope_k(float* __restrict__ qkv,
                                                     const float* __restrict__ qsc,
                                                     const float* __restrict__ ksc,
                                                     const float* __restrict__ cosT,
                                                     const float* __restrict__ sinT) {
  const int t = blockIdx.x;
  const int hh = blockIdx.y;  // 0..31 q heads, 32..35 k heads
  const bool isq = hh < NHQ;
  float* ptr = qkv + (size_t)t * NQKVC + (isq ? hh * HD : NQC + (hh - NHQ) * HD);
  const int i = threadIdx.x;
  float x = ptr[i];
  float ss = x * x;
  ss = wredsum(ss);
  __shared__ float red2[2];
  __shared__ float xs[128];
  if ((i & 63) == 0) red2[i >> 6] = ss;
  __syncthreads();
  float rn = rsqrtf((red2[0] + red2[1]) * (1.f / 128.f) + 1e-6f);
  float xn = x * rn * (isq ? qsc[i] : ksc[i]);
  xs[i] = xn;
  __syncthreads();
  int j = i & 63;
  float c = cosT[t * 64 + j];
  float s = sinT[t * 64 + j];
  float rot = (i < 64) ? -xs[i + 64] : xs[i - 64];
  ptr[i] = xn * c + rot * s;
}

// ---------------- K pre-pass: roped fp32 K -> bf16 hi/lo [hk][t][d] ----------------
__global__ __launch_bounds__(256) void kprep_k(const float* __restrict__ qkv,
                                               bf16_t* __restrict__ Kh,
                                               bf16_t* __restrict__ Kl) {
  const int gid = blockIdx.x * 256 + threadIdx.x;  // 131072 threads
  const int tok = gid >> 6;
  const int c = (gid & 63) * 8;  // 0..504 over 4 heads x 128
  const int hk = c >> 7, d = c & 127;
  const float* p = qkv + (size_t)tok * NQKVC + NQC + c;
  float4 a = *(const float4*)p;
  float4 b = *(const float4*)(p + 4);
  float xv[8] = {a.x, a.y, a.z, a.w, b.x, b.y, b.z, b.w};
  bf16x8 hv, lv;
#pragma unroll
  for (int j = 0; j < 8; j++) {
    bf16_t hi = (bf16_t)xv[j];
    hv[j] = hi;
    lv[j] = (bf16_t)(xv[j] - (float)hi);
  }
  const size_t o = ((size_t)hk * SLEN + tok) * HD + d;
  *(bf16x8*)(Kh + o) = hv;
  *(bf16x8*)(Kl + o) = lv;
}

// ---------------- V pre-pass: fp32 V -> bf16 hi/lo TRANSPOSED [hk][d][t] ----------------
__global__ __launch_bounds__(256) void vprep_k(const float* __restrict__ qkv,
                                               bf16_t* __restrict__ Vh,
                                               bf16_t* __restrict__ Vl) {
  __shared__ float tile[32][33];
  const int hk = blockIdx.z;
  const int tx = threadIdx.x, ty = threadIdx.y;
  const int t0 = blockIdx.x * 32, d0 = blockIdx.y * 32;
#pragma unroll
  for (int i = 0; i < 4; i++)
    tile[ty + i * 8][tx] =
        qkv[(size_t)(t0 + ty + i * 8) * NQKVC + NQC + NKVC + hk * HD + d0 + tx];
  __syncthreads();
#pragma unroll
  for (int i = 0; i < 4; i++) {
    int d = d0 + ty + i * 8;
    int tk = t0 + tx;
    float wv = tile[tx][ty + i * 8];
    bf16_t hi = (bf16_t)wv;
    size_t o = ((size_t)hk * HD + d) * SLEN + tk;
    Vh[o] = hi;
    Vl[o] = (bf16_t)(wv - (float)hi);
  }
}

// ---------------- MFMA flash attention, paired 64-row q tiles, full hi/lo split ----------
// Grid (16, 32): block bx handles q-tiles (31-bx) then (bx) -> every block does
// exactly 33 kv-tile iterations; 512 blocks = exactly 2/CU (LDS 70KB) -> one
// perfectly balanced residency wave (was: 1024 blocks, 32:1 work spread).
// K/V staged from pre-converted hi/lo bf16 buffers (no per-tile fp32->bf16
// VALU, no in-kernel V transpose; V-transpose 8B stores were the dominant
// SQ_LDS_BANK_CONFLICT source).
__global__ __launch_bounds__(256) void attn_mfma_k(const float* __restrict__ qkv,
                                                   const bf16_t* __restrict__ Kph,
                                                   const bf16_t* __restrict__ Kpl,
                                                   const bf16_t* __restrict__ Vph,
                                                   const bf16_t* __restrict__ Vpl,
                                                   bf16_t* __restrict__ attnH,
                                                   bf16_t* __restrict__ attnL) {
  const int bx = blockIdx.x;   // 0..15
  const int hh = blockIdx.y;   // q head
  const int hk = hh >> 3;
  __shared__ bf16_t sK[2][64][KSTR];   // [hi/lo][kv=64][d=128]; P overlays after QK^T
  __shared__ bf16_t sV[2][128][VSTR];  // [hi/lo][d=128][kv=64]
  const int t = threadIdx.x;
  const int w = t >> 6, lane = t & 63;
  const int m16 = lane & 15, quad = lane >> 4;
  const float SCALE = 0.08838834764831845f;  // 1/sqrt(128)

  // staging indices: K rows 16/round (16 lanes x 16B = full 256B row),
  // V rows 32/round (8 lanes x 16B = full 128B row)
  const int ksr = t >> 4;          // 0..15
  const int ksc = (t & 15) * 8;    // 0..120
  const int vsd = t >> 3;          // 0..31
  const int vsk = (t & 7) * 8;     // 0..56
  const bf16_t* KbH = Kph + (size_t)hk * SLEN * HD;
  const bf16_t* KbL = Kpl + (size_t)hk * SLEN * HD;
  const bf16_t* VbH = Vph + (size_t)hk * HD * SLEN;
  const bf16_t* VbL = Vpl + (size_t)hk * HD * SLEN;
  bf16_t* sP = &sK[0][0][0];  // overlay: per-wave [hi/lo][16][PSTR]

  for (int half = 0; half < 2; half++) {
    const int qb = half ? bx : 31 - bx;

    bf16x8 Qh[4], Ql[4];
    {
      const int qrow = qb * 64 + w * 16 + m16;
      const float* qp = qkv + (size_t)qrow * NQKVC + hh * HD + quad * 8;
#pragma unroll
      for (int kc = 0; kc < 4; kc++) {
        float4 x0 = *(const float4*)(qp + kc * 32);
        float4 x1 = *(const float4*)(qp + kc * 32 + 4);
        float xv[8] = {x0.x, x0.y, x0.z, x0.w, x1.x, x1.y, x1.z, x1.w};
#pragma unroll
        for (int j = 0; j < 8; j++) {
          bf16_t hi = (bf16_t)xv[j];
          Qh[kc][j] = hi;
          Ql[kc][j] = (bf16_t)(xv[j] - (float)hi);
        }
      }
    }
    f32x4 acc[8];
#pragma unroll
    for (int i = 0; i < 8; i++) acc[i] = (f32x4){0.f, 0.f, 0.f, 0.f};
    float mrow[4], lrow[4];
#pragma unroll
    for (int r = 0; r < 4; r++) { mrow[r] = -1e30f; lrow[r] = 0.f; }

    for (int kb = 0; kb <= qb; kb++) {
      __syncthreads();
      {  // stage K tile [kv][d] hi/lo (pre-converted)
#pragma unroll
        for (int i = 0; i < 4; i++) {
          const int row = ksr + i * 16;
          const size_t go = (size_t)(kb * 64 + row) * HD + ksc;
          *(bf16x8*)(&sK[0][row][ksc]) = *(const bf16x8*)(KbH + go);
          *(bf16x8*)(&sK[1][row][ksc]) = *(const bf16x8*)(KbL + go);
        }
      }
      {  // stage V tile [d][kv] hi/lo (pre-transposed)
#pragma unroll
        for (int i = 0; i < 4; i++) {
          const int d = vsd + i * 32;
          const size_t go = (size_t)d * SLEN + kb * 64 + vsk;
          *(bf16x8*)(&sV[0][d][vsk]) = *(const bf16x8*)(VbH + go);
          *(bf16x8*)(&sV[1][d][vsk]) = *(const bf16x8*)(VbL + go);
        }
      }
      __syncthreads();
      f32x4 xs[4];
#pragma unroll
      for (int nt = 0; nt < 4; nt++) {
        f32x4 s = (f32x4){0.f, 0.f, 0.f, 0.f};
        if (kb < qb || nt <= w) {
#pragma unroll
          for (int kc = 0; kc < 4; kc++) {
            bf16x8 kh = *(const bf16x8*)(&sK[0][nt * 16 + m16][kc * 32 + quad * 8]);
            bf16x8 kl = *(const bf16x8*)(&sK[1][nt * 16 + m16][kc * 32 + quad * 8]);
            s = __builtin_amdgcn_mfma_f32_16x16x32_bf16(Qh[kc], kh, s, 0, 0, 0);
            s = __builtin_amdgcn_mfma_f32_16x16x32_bf16(Ql[kc], kh, s, 0, 0, 0);
            s = __builtin_amdgcn_mfma_f32_16x16x32_bf16(Qh[kc], kl, s, 0, 0, 0);
          }
        }
        xs[nt] = s;
      }
      __syncthreads();
      float p[4][4], alpha[4];
#pragma unroll
      for (int r = 0; r < 4; r++) {
        const int rqg = qb * 64 + w * 16 + quad * 4 + r;
        float xr[4];
#pragma unroll
        for (int nt = 0; nt < 4; nt++) {
          int colg = kb * 64 + nt * 16 + m16;
          xr[nt] = (colg <= rqg) ? xs[nt][r] * SCALE : -1e30f;
        }
        float mx = fmaxf(fmaxf(xr[0], xr[1]), fmaxf(xr[2], xr[3]));
#pragma unroll
        for (int off = 1; off < 16; off <<= 1) mx = fmaxf(mx, __shfl_xor(mx, off));
        float mn = fmaxf(mrow[r], mx);
        float al = __expf(mrow[r] - mn);
        float rs = 0.f;
#pragma unroll
        for (int nt = 0; nt < 4; nt++) {
          float pv = __expf(xr[nt] - mn);
          p[nt][r] = pv;
          rs += pv;
        }
#pragma unroll
        for (int off = 1; off < 16; off <<= 1) rs += __shfl_xor(rs, off);
        lrow[r] = lrow[r] * al + rs;
        mrow[r] = mn;
        alpha[r] = al;
      }
#pragma unroll
      for (int dt = 0; dt < 8; dt++)
#pragma unroll
        for (int r = 0; r < 4; r++) acc[dt][r] *= alpha[r];
      {
        bf16_t* base = sP + (size_t)w * 2 * 16 * PSTR;
#pragma unroll
        for (int nt = 0; nt < 4; nt++)
#pragma unroll
          for (int r = 0; r < 4; r++) {
            float pv = p[nt][r];
            bf16_t hi = (bf16_t)pv;
            base[(quad * 4 + r) * PSTR + nt * 16 + m16] = hi;
            base[16 * PSTR + (quad * 4 + r) * PSTR + nt * 16 + m16] = (bf16_t)(pv - (float)hi);
          }
      }
      {
        const bf16_t* base = sP + (size_t)w * 2 * 16 * PSTR;
        bf16x8 Ph[2], Pl[2];
#pragma unroll
        for (int kc = 0; kc < 2; kc++) {
          Ph[kc] = *(const bf16x8*)(base + m16 * PSTR + kc * 32 + quad * 8);
          Pl[kc] = *(const bf16x8*)(base + 16 * PSTR + m16 * PSTR + kc * 32 + quad * 8);
        }
#pragma unroll
        for (int dt = 0; dt < 8; dt++)
#pragma unroll
          for (int kc = 0; kc < 2; kc++) {
            bf16x8 vh = *(const bf16x8*)(&sV[0][dt * 16 + m16][kc * 32 + quad * 8]);
            bf16x8 vl = *(const bf16x8*)(&sV[1][dt * 16 + m16][kc * 32 + quad * 8]);
            acc[dt] = __builtin_amdgcn_mfma_f32_16x16x32_bf16(Ph[kc], vh, acc[dt], 0, 0, 0);
            acc[dt] = __builtin_amdgcn_mfma_f32_16x16x32_bf16(Pl[kc], vh, acc[dt], 0, 0, 0);
            acc[dt] = __builtin_amdgcn_mfma_f32_16x16x32_bf16(Ph[kc], vl, acc[dt], 0, 0, 0);
          }
      }
    }
#pragma unroll
    for (int r = 0; r < 4; r++) {
      const int tok = qb * 64 + w * 16 + quad * 4 + r;
      const float linv = 1.f / lrow[r];
      const size_t ro = (size_t)tok * NQC + hh * HD;
#pragma unroll
      for (int dt = 0; dt < 8; dt++) {
        float v = acc[dt][r] * linv;
        bf16_t hi = (bf16_t)v;
        attnH[ro + dt * 16 + m16] = hi;
        attnL[ro + dt * 16 + m16] = (bf16_t)(v - (float)hi);
      }
    }
  }
}

// ---------------- rmsnorm2 + router logits (fp32, deterministic) ----------------
__global__ __launch_bounds__(256) void rmsnorm2_router_k(const float* __restrict__ hid,
                                                         const float* __restrict__ sc2,
                                                         const float* __restrict__ rW,
                                                         bf16_t* __restrict__ xf,
                                                         float* __restrict__ rlog) {
  const int t = blockIdx.x;
  const float* row = hid + (size_t)t * DMOD;
  const int tid = threadIdx.x;
  const int i0 = tid * 8;
  float4 a = *(const float4*)(row + i0);
  float4 b = *(const float4*)(row + i0 + 4);
  float x[8] = {a.x, a.y, a.z, a.w, b.x, b.y, b.z, b.w};
  float ss = 0.f;
#pragma unroll
  for (int j = 0; j < 8; j++) ss += x[j] * x[j];
  ss = wredsum(ss);
  __shared__ float red[4];
  if ((tid & 63) == 0) red[tid >> 6] = ss;
  __syncthreads();
  float rn = rsqrtf((red[0] + red[1] + red[2] + red[3]) * (1.f / 2048.f) + 1e-6f);
  float acc[8];
#pragma unroll
  for (int e = 0; e < 8; e++) acc[e] = 0.f;
#pragma unroll
  for (int j = 0; j < 8; j++) {
    float xn = x[j] * rn * sc2[i0 + j];
    xf[(size_t)t * DMOD + i0 + j] = (bf16_t)xn;
    const float* w = rW + (size_t)(i0 + j) * NEXP;
#pragma unroll
    for (int e = 0; e < 8; e++) acc[e] += xn * w[e];
  }
#pragma unroll
  for (int e = 0; e < 8; e++) acc[e] = wredsum(acc[e]);
  __shared__ float wacc[4][8];
  if ((tid & 63) == 0)
#pragma unroll
    for (int e = 0; e < 8; e++) wacc[tid >> 6][e] = acc[e];
  __syncthreads();
  if (tid < 8) rlog[t * NEXP + tid] = wacc[0][tid] + wacc[1][tid] + wacc[2][tid] + wacc[3][tid];
}

// ---------------- top-2 selection + gates; aux_loss == 1.0 analytically ----------------
__global__ void topk_k(const float* __restrict__ rlog, int* __restrict__ sel,
                       float* __restrict__ gates, float* __restrict__ aux) {
  int t = blockIdx.x * 256 + threadIdx.x;
  if (t == 0) aux[0] = 1.0f;
  if (t >= SLEN) return;
  const float* l = rlog + t * NEXP;
  int i1 = 0; float v1 = l[0];
#pragma unroll
  for (int e = 1; e < 8; e++) if (l[e] > v1) { v1 = l[e]; i1 = e; }
  int i2 = -1; float v2 = -1e30f;
#pragma unroll
  for (int e = 0; e < 8; e++) if (e != i1 && l[e] > v2) { v2 = l[e]; i2 = e; }
  float e21 = expf(v2 - v1);
  float inv = 1.f / (1.f + e21);
  sel[t * 2 + 0] = i1;
  sel[t * 2 + 1] = i2;
  gates[t * 2 + 0] = inv;
  gates[t * 2 + 1] = e21 * inv;
}

// ---------------- scatter tokens to per-expert lists ----------------
__global__ void scatter_k(const int* __restrict__ sel, const float* __restrict__ gates,
                          int* __restrict__ cnt, int* __restrict__ tok,
                          float* __restrict__ gateL) {
  int i = blockIdx.x * 256 + threadIdx.x;
  if (i >= SLEN * 2) return;
  int e = sel[i];
  int pos = atomicAdd(&cnt[e], 1);
  tok[e * SLEN + pos] = i >> 1;
  gateL[e * SLEN + pos] = gates[i];
}

// ---------------- MoE up-GEMM (gathered rows, silu+bias epilogue, bf16 out) ----------------
__global__ __launch_bounds__(256) void gemm_up_k(const bf16_t* __restrict__ xf,
                                                 const bf16_t* __restrict__ upWT,
                                                 const int* __restrict__ cnt,
                                                 const int* __restrict__ tok,
                                                 const float* __restrict__ up_b,
                                                 bf16_t* __restrict__ hbuf) {
  const int e = blockIdx.z;
  const int c = cnt[e];
  const int m0 = blockIdx.y * 64;
  if (m0 >= c) return;
  const int n0 = blockIdx.x * 64;
  const int* tokE = tok + e * SLEN;
  const bf16_t* BtE = upWT + (size_t)e * NF * DMOD;
  f32x4 zz = {0.f, 0.f, 0.f, 0.f};
  f32x4 acc[4] = {zz, zz, zz, zz};
  gemm_core([=](int r) {
      int s = m0 + r; if (s >= c) s = c - 1;
      return xf + (size_t)tokE[s] * DMOD;
    }, BtE, DMOD, n0, DMOD, acc);
  const int t = threadIdx.x, wave = t >> 6, lane = t & 63;
  const int m16 = lane & 15, quad = lane >> 4;
  const int mb = m0 + wave * 16 + quad * 4;
  const int nb = n0 + m16;
#pragma unroll
  for (int nt = 0; nt < 4; nt++)
#pragma unroll
    for (int r = 0; r < 4; r++) {
      int slot = mb + r;
      if (slot < c) {
        int n = nb + nt * 16;
        float x = acc[nt][r] + up_b[e * NF + n];
        float v = x / (1.f + __expf(-x));
        hbuf[((size_t)e * SLEN + slot) * NF + n] = (bf16_t)v;
      }
    }
}

// ---------------- MoE down-GEMM (bias + gate, atomicAdd into final hidden) ----------------
__global__ __launch_bounds__(256) void gemm_down_k(const bf16_t* __restrict__ hbuf,
                                                   const bf16_t* __restrict__ downWT,
                                                   const int* __restrict__ cnt,
                                                   const int* __restrict__ tok,
                                                   const float* __restrict__ gateL,
                                                   const float* __restrict__ down_b,
                                                   float* __restrict__ outH) {
  const int e = blockIdx.z;
  const int c = cnt[e];
  const int m0 = blockIdx.y * 64;
  if (m0 >= c) return;
  const int n0 = blockIdx.x * 64;
  const bf16_t* Ah = hbuf + (size_t)e * SLEN * NF;
  const bf16_t* BtE = downWT + (size_t)e * DMOD * NF;
  f32x4 zz = {0.f, 0.f, 0.f, 0.f};
  f32x4 acc[4] = {zz, zz, zz, zz};
  gemm_core([=](int r) { return Ah + (size_t)(m0 + r) * NF; }, BtE, NF, n0, NF, acc);
  const int t = threadIdx.x, wave = t >> 6, lane = t & 63;
  const int m16 = lane & 15, quad = lane >> 4;
  const int mb = m0 + wave * 16 + quad * 4;
  const int nb = n0 + m16;
#pragma unroll
  for (int nt = 0; nt < 4; nt++)
#pragma unroll
    for (int r = 0; r < 4; r++) {
      int slot = mb + r;
      if (slot < c) {
        int n = nb + nt * 16;
        int tk = tok[e * SLEN + slot];
        float g = gateL[e * SLEN + slot];
        atomicAdd(&outH[(size_t)tk * DMOD + n], g * (acc[nt][r] + down_b[e * DMOD + n]));
      }
    }
}

// ---------------- host ----------------
extern "C" void kernel_launch(void* const* d_in, const int* in_sizes, int n_in,
                              void* d_out, int out_size, void* d_ws, size_t ws_size,
                              hipStream_t stream) {
  (void)in_sizes; (void)n_in; (void)out_size;
  const float* hs   = (const float*)d_in[0];
  const float* ln1  = (const float*)d_in[1];
  const float* ln2  = (const float*)d_in[2];
  const float* Wq   = (const float*)d_in[3];
  const float* Wk   = (const float*)d_in[4];
  const float* Wv   = (const float*)d_in[5];
  const float* Wo   = (const float*)d_in[6];
  const float* qns  = (const float*)d_in[7];
  const float* kns  = (const float*)d_in[8];
  const float* rW   = (const float*)d_in[9];
  const float* upW  = (const float*)d_in[10];
  const float* upB  = (const float*)d_in[11];
  const float* dnW  = (const float*)d_in[12];
  const float* dnB  = (const float*)d_in[13];
  float* dout = (float*)d_out;

  // ---- workspace layout with lifetime overlays (total ~135.5 MB) ----
  const size_t NEED = 135431168ull;
  if (ws_size < NEED) return;  // clean failure instead of OOB crash
  char* ws = (char*)d_ws;
  const size_t OA = 0;
  const size_t OB = OA + 41943040ull;
  const size_t OC = OB + 33554432ull;
  const size_t OD = OC + 16777216ull;
  const size_t OE = OD + 41943040ull;

  bf16_t* BqkvH  = (bf16_t*)(ws + OA);
  bf16_t* BqkvL  = (bf16_t*)(ws + OA + 20971520ull);
  bf16_t* attnH  = (bf16_t*)(ws + OA);
  bf16_t* attnL  = (bf16_t*)(ws + OA + 16777216ull);
  // K/V pre-pass buffers: live only from kprep/vprep until end of attn;
  // occupy the free tail of OA after Bqkv dies (attnH+attnL = 33.5MB of 41.9MB).
  bf16_t* Kph    = (bf16_t*)(ws + OA + 33554432ull);  // 4*2048*128*2B = 2MB
  bf16_t* Kpl    = Kph + 1048576;
  bf16_t* Vph    = Kpl + 1048576;                     // transposed [hk][d][t]
  bf16_t* Vpl    = Vph + 1048576;
  bf16_t* upWT   = (bf16_t*)(ws + OA);
  bf16_t* WoH    = (bf16_t*)(ws + OB);
  bf16_t* WoL    = (bf16_t*)(ws + OB + 16777216ull);
  bf16_t* hbuf   = (bf16_t*)(ws + OB);
  bf16_t* xnH    = (bf16_t*)(ws + OC);
  bf16_t* xnL    = (bf16_t*)(ws + OC + 8388608ull);
  bf16_t* xf     = (bf16_t*)(ws + OC);
  float*  qkv    = (float*)(ws + OD);
  bf16_t* downWT = (bf16_t*)(ws + OD);
  float*  cosT   = (float*)(ws + OE);
  float*  sinT   = (float*)(ws + OE + 524288ull);
  int*    sel    = (int*)(ws + OE + 1048576ull);
  float*  gates  = (float*)(ws + OE + 1064960ull);
  int*    cnt    = (int*)(ws + OE + 1081344ull);
  int*    tok    = (int*)(ws + OE + 1082368ull);
  float*  gateL  = (float*)(ws + OE + 1147904ull);

  hipMemsetAsync(cnt, 0, 1024, stream);
  rope_table_k<<<512, 256, 0, stream>>>(cosT, sinT);

  dim3 tb(32, 8);
  transpose_split2_k<<<dim3(128, 64), tb, 0, stream>>>(Wq, BqkvH, BqkvL, 2048, 4096);
  transpose_split2_k<<<dim3(16, 64), tb, 0, stream>>>(Wk, BqkvH + (size_t)4096 * 2048,
                                                      BqkvL + (size_t)4096 * 2048, 2048, 512);
  transpose_split2_k<<<dim3(16, 64), tb, 0, stream>>>(Wv, BqkvH + (size_t)4608 * 2048,
                                                      BqkvL + (size_t)4608 * 2048, 2048, 512);
  transpose_split2_k<<<dim3(64, 128), tb, 0, stream>>>(Wo, WoH, WoL, 4096, 2048);

  rmsnorm1_k<<<2048, 256, 0, stream>>>(hs, ln1, xnH, xnL);
  gemm_split128_k<false><<<dim3(40, 16), 256, 0, stream>>>(xnH, xnL, 2048, BqkvH, BqkvL,
                                                           2048, 2048, nullptr, qkv, NQKVC);
  qknorm_rope_k<<<dim3(2048, 36), 128, 0, stream>>>(qkv, qns, kns, cosT, sinT);
  kprep_k<<<512, 256, 0, stream>>>(qkv, Kph, Kpl);
  vprep_k<<<dim3(64, 4, 4), tb, 0, stream>>>(qkv, Vph, Vpl);
  attn_mfma_k<<<dim3(16, 32), 256, 0, stream>>>(qkv, Kph, Kpl, Vph, Vpl, attnH, attnL);
  gemm_split128_k<true><<<dim3(16, 16), 256, 0, stream>>>(attnH, attnL, 4096, WoH, WoL,
                                                          4096, 4096, hs, dout, DMOD);

  rmsnorm2_router_k<<<2048, 256, 0, stream>>>(dout, ln2, rW, xf, dout + 4194304);
  topk_k<<<8, 256, 0, stream>>>(dout + 4194304, sel, gates, dout + 4210688);
  scatter_k<<<16, 256, 0, stream>>>(sel, gates, cnt, tok, gateL);

  transpose_plain_k<<<dim3(24, 64, 8), tb, 0, stream>>>(upW, upWT, 2048, 768);
  transpose_plain_k<<<dim3(64, 24, 8), tb, 0, stream>>>(dnW, downWT, 768, 2048);

  gemm_up_k<<<dim3(12, 32, 8), 256, 0, stream>>>(xf, upWT, cnt, tok, upB, hbuf);
  gemm_down_k<<<dim3(32, 32, 8), 256, 0, stream>>>(hbuf, downWT, cnt, tok, gateL, dnB, dout);
}

// Round 2
// 925.984 us; speedup vs baseline: 1.2051x; 1.0010x over previous
//
#include <hip/hip_runtime.h>
#include <cmath>

typedef __bf16 bf16_t;
typedef __bf16 bf16x8 __attribute__((ext_vector_type(8)));
typedef __bf16 bf16x4 __attribute__((ext_vector_type(4)));
typedef float  f32x4  __attribute__((ext_vector_type(4)));

#define SLEN 2048
#define DMOD 2048
#define NHQ  32
#define NHKV 4
#define HD   128
#define NQC  4096
#define NKVC 512
#define NQKVC 5120
#define NEXP 8
#define NF   768

// LDS strides for attention tiles (see round-4 note: inner dim >= full tile
// extent, stride % 8 == 0 for aligned ds_read_b128).
#define KSTR 136
#define VSTR 72
#define PSTR 72

// ---------------- helpers ----------------
__device__ __forceinline__ float wredsum(float v) {
#pragma unroll
  for (int off = 32; off > 0; off >>= 1) v += __shfl_xor(v, off);
  return v;
}

// async global->LDS, 16 B per lane. LDS dest is wave-uniform base + lane*16
// (HW rule) -> pass a wave-uniform LDS pointer; per-lane global pointers.
__device__ __forceinline__ void gll16(const bf16_t* g, bf16_t* l) {
  __builtin_amdgcn_global_load_lds((const __attribute__((address_space(1))) void*)g,
                                   (__attribute__((address_space(3))) void*)l, 16, 0, 0);
}

// ---------------- rope table (fp64 for accuracy) ----------------
__global__ void rope_table_k(float* __restrict__ cosT, float* __restrict__ sinT) {
  int idx = blockIdx.x * 256 + threadIdx.x;
  if (idx >= SLEN * 64) return;
  int t = idx >> 6, j = idx & 63;
  double inv = exp(-0.2158673524681918 * (double)j);  // ln(1e6)/64
  double ang = (double)t * inv;
  cosT[idx] = (float)cos(ang);
  sinT[idx] = (float)sin(ang);
}

// ---------------- weight transpose: fp32 [R][C] -> bf16 hi/lo pair [C][R] ----------------
__global__ __launch_bounds__(256) void transpose_split2_k(const float* __restrict__ in,
                                                          bf16_t* __restrict__ outH,
                                                          bf16_t* __restrict__ outL,
                                                          int R, int C) {
  __shared__ float tile[32][33];
  int tx = threadIdx.x, ty = threadIdx.y;
  int c0 = blockIdx.x * 32, r0 = blockIdx.y * 32;
#pragma unroll
  for (int i = 0; i < 4; i++)
    tile[ty + i * 8][tx] = in[(size_t)(r0 + ty + i * 8) * C + c0 + tx];
  __syncthreads();
#pragma unroll
  for (int i = 0; i < 4; i++) {
    int c = c0 + ty + i * 8;
    int r = r0 + tx;
    float w = tile[tx][ty + i * 8];
    bf16_t hi = (bf16_t)w;
    bf16_t lo = (bf16_t)(w - (float)hi);
    size_t o = (size_t)c * R + r;
    outH[o] = hi;
    outL[o] = lo;
  }
}

// ---------------- plain transpose: fp32 [b][R][C] -> bf16 [b][C][R] ----------------
__global__ __launch_bounds__(256) void transpose_plain_k(const float* __restrict__ in,
                                                         bf16_t* __restrict__ out,
                                                         int R, int C) {
  __shared__ float tile[32][33];
  int b = blockIdx.z;
  const float* inb = in + (size_t)b * R * C;
  bf16_t* outb = out + (size_t)b * R * C;
  int tx = threadIdx.x, ty = threadIdx.y;
  int c0 = blockIdx.x * 32, r0 = blockIdx.y * 32;
#pragma unroll
  for (int i = 0; i < 4; i++)
    tile[ty + i * 8][tx] = inb[(size_t)(r0 + ty + i * 8) * C + c0 + tx];
  __syncthreads();
#pragma unroll
  for (int i = 0; i < 4; i++) {
    int c = c0 + ty + i * 8;
    int r = r0 + tx;
    outb[(size_t)c * R + r] = (bf16_t)tile[tx][ty + i * 8];
  }
}

// ---------------- rmsnorm1: fp32 row -> bf16 hi/lo pair [t][2048] ----------------
__global__ __launch_bounds__(256) void rmsnorm1_k(const float* __restrict__ hs,
                                                  const float* __restrict__ sc,
                                                  bf16_t* __restrict__ xnH,
                                                  bf16_t* __restrict__ xnL) {
  const int t = blockIdx.x;
  const float* row = hs + (size_t)t * DMOD;
  const int tid = threadIdx.x;
  const int i0 = tid * 8;
  float4 a = *(const float4*)(row + i0);
  float4 b = *(const float4*)(row + i0 + 4);
  float x[8] = {a.x, a.y, a.z, a.w, b.x, b.y, b.z, b.w};
  float ss = 0.f;
#pragma unroll
  for (int j = 0; j < 8; j++) ss += x[j] * x[j];
  ss = wredsum(ss);
  __shared__ float red[4];
  if ((tid & 63) == 0) red[tid >> 6] = ss;
  __syncthreads();
  float rn = rsqrtf((red[0] + red[1] + red[2] + red[3]) * (1.f / 2048.f) + 1e-6f);
#pragma unroll
  for (int j = 0; j < 8; j++) {
    float v = x[j] * rn * sc[i0 + j];
    bf16_t hi = (bf16_t)v;
    bf16_t lo = (bf16_t)(v - (float)hi);
    xnH[(size_t)t * DMOD + i0 + j] = hi;
    xnL[(size_t)t * DMOD + i0 + j] = lo;
  }
}

// ---------------- 128x128 split MFMA GEMM, double-buffered counted-vmcnt pipeline ------
// 4 waves in 2x2; each wave owns a 64x64 quadrant = 4x4 MFMA tiles, 3 MFMA per
// fragment pair (hi*hi + lo*hi + hi*lo).
// Round-2 change: LDS double-buffer (2x32KB) + raw s_barrier + counted
// s_waitcnt vmcnt(8) so the 8 global_load_lds for tile t+1 stay in flight
// under tile t's 48 MFMAs (T3/T4 minimum form; the old __syncthreads drained
// vmcnt(0) every K-step = the documented ~2x m97-structure stall).
// No other VMEM ops inside the loop -> counted-vmcnt discipline is sound.
// Also: XCD-chunked block swizzle (T1) so each XCD keeps its A-panel in L2.
template <bool RESID>
__global__ __launch_bounds__(256) void gemm_split128_k(const bf16_t* __restrict__ Ah,
                                                       const bf16_t* __restrict__ Al,
                                                       int lda,
                                                       const bf16_t* __restrict__ Bh,
                                                       const bf16_t* __restrict__ Bl,
                                                       int ldb, int K,
                                                       const float* __restrict__ resid,
                                                       float* __restrict__ C, int ldc) {
  __shared__ bf16_t AsH[2][128][32], AsL[2][128][32], BsH[2][128][32], BsL[2][128][32];
  const int t = threadIdx.x;
  const int w = t >> 6, lane = t & 63;
  const int m16 = lane & 15, quad = lane >> 4;
  // XCD-chunked swizzle (bijective when nwg % 8 == 0; both call sites are).
  const int nwg = gridDim.x * gridDim.y;
  const int flat = blockIdx.y * gridDim.x + blockIdx.x;
  int tile = flat;
  if ((nwg & 7) == 0) tile = (flat & 7) * (nwg >> 3) + (flat >> 3);
  const int bx = tile % gridDim.x, by = tile / gridDim.x;
  const int m0 = by * 128, n0 = bx * 128;
  const int wm = (w & 1) * 64, wn = (w >> 1) * 64;
  f32x4 acc[4][4];
#pragma unroll
  for (int i = 0; i < 4; i++)
#pragma unroll
    for (int j = 0; j < 4; j++) acc[i][j] = (f32x4){0.f, 0.f, 0.f, 0.f};

  const int srow = t >> 2;         // 0..63
  const int scol = (t & 3) * 8;    // element col within BK=32
  const int lw = w * 512;          // wave-uniform LDS elem offset
  const bf16_t* gAh0 = Ah + (size_t)(m0 + srow) * lda + scol;
  const bf16_t* gAh1 = Ah + (size_t)(m0 + 64 + srow) * lda + scol;
  const bf16_t* gAl0 = Al + (size_t)(m0 + srow) * lda + scol;
  const bf16_t* gAl1 = Al + (size_t)(m0 + 64 + srow) * lda + scol;
  const bf16_t* gBh0 = Bh + (size_t)(n0 + srow) * ldb + scol;
  const bf16_t* gBh1 = Bh + (size_t)(n0 + 64 + srow) * ldb + scol;
  const bf16_t* gBl0 = Bl + (size_t)(n0 + srow) * ldb + scol;
  const bf16_t* gBl1 = Bl + (size_t)(n0 + 64 + srow) * ldb + scol;

  auto stage = [&](int buf, int k0) {
    gll16(gAh0 + k0, &AsH[buf][0][0] + lw);
    gll16(gAh1 + k0, &AsH[buf][0][0] + 2048 + lw);
    gll16(gAl0 + k0, &AsL[buf][0][0] + lw);
    gll16(gAl1 + k0, &AsL[buf][0][0] + 2048 + lw);
    gll16(gBh0 + k0, &BsH[buf][0][0] + lw);
    gll16(gBh1 + k0, &BsH[buf][0][0] + 2048 + lw);
    gll16(gBl0 + k0, &BsL[buf][0][0] + lw);
    gll16(gBl1 + k0, &BsL[buf][0][0] + 2048 + lw);
  };

  stage(0, 0);
  int cur = 0;
  for (int k0 = 32; k0 <= K; k0 += 32) {
    if (k0 < K) {
      stage(cur ^ 1, k0);
      asm volatile("s_waitcnt vmcnt(8)" ::: "memory");  // wait tile(cur); keep 8 in flight
    } else {
      asm volatile("s_waitcnt vmcnt(0)" ::: "memory");  // final drain
    }
    __builtin_amdgcn_sched_barrier(0);
    __builtin_amdgcn_s_barrier();
    __builtin_amdgcn_sched_barrier(0);
    bf16x8 a_h[4], a_l[4];
#pragma unroll
    for (int mt = 0; mt < 4; mt++) {
      a_h[mt] = *(const bf16x8*)(&AsH[cur][wm + mt * 16 + m16][quad * 8]);
      a_l[mt] = *(const bf16x8*)(&AsL[cur][wm + mt * 16 + m16][quad * 8]);
    }
#pragma unroll
    for (int nt = 0; nt < 4; nt++) {
      bf16x8 b_h = *(const bf16x8*)(&BsH[cur][wn + nt * 16 + m16][quad * 8]);
      bf16x8 b_l = *(const bf16x8*)(&BsL[cur][wn + nt * 16 + m16][quad * 8]);
#pragma unroll
      for (int mt = 0; mt < 4; mt++) {
        acc[mt][nt] = __builtin_amdgcn_mfma_f32_16x16x32_bf16(a_h[mt], b_h, acc[mt][nt], 0, 0, 0);
        acc[mt][nt] = __builtin_amdgcn_mfma_f32_16x16x32_bf16(a_l[mt], b_h, acc[mt][nt], 0, 0, 0);
        acc[mt][nt] = __builtin_amdgcn_mfma_f32_16x16x32_bf16(a_h[mt], b_l, acc[mt][nt], 0, 0, 0);
      }
    }
    // all LDS reads of buf[cur] have landed (lgkm waits precede the MFMAs);
    // barrier before next iter overwrites buf[cur^1]... (next stage targets
    // the buffer just read by the *previous* iteration -> guarded here).
    __builtin_amdgcn_sched_barrier(0);
    __builtin_amdgcn_s_barrier();
    __builtin_amdgcn_sched_barrier(0);
    cur ^= 1;
  }
  // epilogue: C row = m0+wm+mt*16+quad*4+r, col = n0+wn+nt*16+m16
#pragma unroll
  for (int mt = 0; mt < 4; mt++)
#pragma unroll
    for (int r = 0; r < 4; r++) {
      const size_t row = m0 + wm + mt * 16 + quad * 4 + r;
#pragma unroll
      for (int nt = 0; nt < 4; nt++) {
        const size_t idx = row * ldc + n0 + wn + nt * 16 + m16;
        if (RESID) C[idx] = acc[mt][nt][r] + resid[idx];
        else       C[idx] = acc[mt][nt][r];
      }
    }
}

// ---------------- plain MFMA GEMM core (MoE, bf16 single) ----------------
template <class AROW>
__device__ __forceinline__ void gemm_core(AROW getA, const bf16_t* __restrict__ Bt, int ldb,
                                          int n0, int K, f32x4 acc[4]) {
  __shared__ bf16_t As[64][32];
  __shared__ bf16_t Bs[64][32];
  const int t = threadIdx.x;
  const int wave = t >> 6, lane = t & 63;
  const int m16 = lane & 15, quad = lane >> 4;
  const int sr = t >> 2, sc = (t & 3) << 3;
  const bf16_t* __restrict__ arow = getA(sr);
  const bf16_t* __restrict__ brow = Bt + (size_t)(n0 + sr) * ldb;
  for (int k0 = 0; k0 < K; k0 += 32) {
    __syncthreads();
    *(uint4*)(&As[sr][sc]) = *(const uint4*)(arow + k0 + sc);
    *(uint4*)(&Bs[sr][sc]) = *(const uint4*)(brow + k0 + sc);
    __syncthreads();
    bf16x8 af = *(const bf16x8*)(&As[wave * 16 + m16][quad * 8]);
#pragma unroll
    for (int nt = 0; nt < 4; nt++) {
      bf16x8 bfr = *(const bf16x8*)(&Bs[nt * 16 + m16][quad * 8]);
      acc[nt] = __builtin_amdgcn_mfma_f32_16x16x32_bf16(af, bfr, acc[nt], 0, 0, 0);
    }
  }
}

// ---------------- qk-norm + rope, IN-PLACE on fp32 qkv ----------------
__global__ __launch_bounds__(128) void qknorm_rope_k(float* __restrict__ qkv,
                                                     const float* __restrict__ qsc,
                                                     const float* __restrict__ ksc,
                                                     const float* __restrict__ cosT,
                                                     const float* __restrict__ sinT) {
  const int t = blockIdx.x;
  const int hh = blockIdx.y;  // 0..31 q heads, 32..35 k heads
  const bool isq = hh < NHQ;
  float* ptr = qkv + (size_t)t * NQKVC + (isq ? hh * HD : NQC + (hh - NHQ) * HD);
  const int i = threadIdx.x;
  float x = ptr[i];
  float ss = x * x;
  ss = wredsum(ss);
  __shared__ float red2[2];
  __shared__ float xs[128];
  if ((i & 63) == 0) red2[i >> 6] = ss;
  __syncthreads();
  float rn = rsqrtf((red2[0] + red2[1]) * (1.f / 128.f) + 1e-6f);
  float xn = x * rn * (isq ? qsc[i] : ksc[i]);
  xs[i] = xn;
  __syncthreads();
  int j = i & 63;
  float c = cosT[t * 64 + j];
  float s = sinT[t * 64 + j];
  float rot = (i < 64) ? -xs[i + 64] : xs[i - 64];
  ptr[i] = xn * c + rot * s;
}

// ---------------- K pre-pass: roped fp32 K -> bf16 hi/lo [hk][t][d] ----------------
__global__ __launch_bounds__(256) void kprep_k(const float* __restrict__ qkv,
                                               bf16_t* __restrict__ Kh,
                                               bf16_t* __restrict__ Kl) {
  const int gid = blockIdx.x * 256 + threadIdx.x;  // 131072 threads
  const int tok = gid >> 6;
  const int c = (gid & 63) * 8;  // 0..504 over 4 heads x 128
  const int hk = c >> 7, d = c & 127;
  const float* p = qkv + (size_t)tok * NQKVC + NQC + c;
  float4 a = *(const float4*)p;
  float4 b = *(const float4*)(p + 4);
  float xv[8] = {a.x, a.y, a.z, a.w, b.x, b.y, b.z, b.w};
  bf16x8 hv, lv;
#pragma unroll
  for (int j = 0; j < 8; j++) {
    bf16_t hi = (bf16_t)xv[j];
    hv[j] = hi;
    lv[j] = (bf16_t)(xv[j] - (float)hi);
  }
  const size_t o = ((size_t)hk * SLEN + tok) * HD + d;
  *(bf16x8*)(Kh + o) = hv;
  *(bf16x8*)(Kl + o) = lv;
}

// ---------------- V pre-pass: fp32 V -> bf16 hi/lo TRANSPOSED [hk][d][t] ----------------
__global__ __launch_bounds__(256) void vprep_k(const float* __restrict__ qkv,
                                               bf16_t* __restrict__ Vh,
                                               bf16_t* __restrict__ Vl) {
  __shared__ float tile[32][33];
  const int hk = blockIdx.z;
  const int tx = threadIdx.x, ty = threadIdx.y;
  const int t0 = blockIdx.x * 32, d0 = blockIdx.y * 32;
#pragma unroll
  for (int i = 0; i < 4; i++)
    tile[ty + i * 8][tx] =
        qkv[(size_t)(t0 + ty + i * 8) * NQKVC + NQC + NKVC + hk * HD + d0 + tx];
  __syncthreads();
#pragma unroll
  for (int i = 0; i < 4; i++) {
    int d = d0 + ty + i * 8;
    int tk = t0 + tx;
    float wv = tile[tx][ty + i * 8];
    bf16_t hi = (bf16_t)wv;
    size_t o = ((size_t)hk * HD + d) * SLEN + tk;
    Vh[o] = hi;
    Vl[o] = (bf16_t)(wv - (float)hi);
  }
}

// ---------------- MFMA flash attention, paired 64-row q tiles, full hi/lo split ----------
// Grid (16, 32): block bx handles q-tiles (31-bx) then (bx) -> every block does
// exactly 33 kv-tile iterations; 512 blocks = exactly 2/CU (LDS 70KB) -> one
// perfectly balanced residency wave.
__global__ __launch_bounds__(256) void attn_mfma_k(const float* __restrict__ qkv,
                                                   const bf16_t* __restrict__ Kph,
                                                   const bf16_t* __restrict__ Kpl,
                                                   const bf16_t* __restrict__ Vph,
                                                   const bf16_t* __restrict__ Vpl,
                                                   bf16_t* __restrict__ attnH,
                                                   bf16_t* __restrict__ attnL) {
  const int bx = blockIdx.x;   // 0..15
  const int hh = blockIdx.y;   // q head
  const int hk = hh >> 3;
  __shared__ bf16_t sK[2][64][KSTR];   // [hi/lo][kv=64][d=128]; P overlays after QK^T
  __shared__ bf16_t sV[2][128][VSTR];  // [hi/lo][d=128][kv=64]
  const int t = threadIdx.x;
  const int w = t >> 6, lane = t & 63;
  const int m16 = lane & 15, quad = lane >> 4;
  const float SCALE = 0.08838834764831845f;  // 1/sqrt(128)

  const int ksr = t >> 4;          // 0..15
  const int ksc = (t & 15) * 8;    // 0..120
  const int vsd = t >> 3;          // 0..31
  const int vsk = (t & 7) * 8;     // 0..56
  const bf16_t* KbH = Kph + (size_t)hk * SLEN * HD;
  const bf16_t* KbL = Kpl + (size_t)hk * SLEN * HD;
  const bf16_t* VbH = Vph + (size_t)hk * HD * SLEN;
  const bf16_t* VbL = Vpl + (size_t)hk * HD * SLEN;
  bf16_t* sP = &sK[0][0][0];  // overlay: per-wave [hi/lo][16][PSTR]

  for (int half = 0; half < 2; half++) {
    const int qb = half ? bx : 31 - bx;

    bf16x8 Qh[4], Ql[4];
    {
      const int qrow = qb * 64 + w * 16 + m16;
      const float* qp = qkv + (size_t)qrow * NQKVC + hh * HD + quad * 8;
#pragma unroll
      for (int kc = 0; kc < 4; kc++) {
        float4 x0 = *(const float4*)(qp + kc * 32);
        float4 x1 = *(const float4*)(qp + kc * 32 + 4);
        float xv[8] = {x0.x, x0.y, x0.z, x0.w, x1.x, x1.y, x1.z, x1.w};
#pragma unroll
        for (int j = 0; j < 8; j++) {
          bf16_t hi = (bf16_t)xv[j];
          Qh[kc][j] = hi;
          Ql[kc][j] = (bf16_t)(xv[j] - (float)hi);
        }
      }
    }
    f32x4 acc[8];
#pragma unroll
    for (int i = 0; i < 8; i++) acc[i] = (f32x4){0.f, 0.f, 0.f, 0.f};
    float mrow[4], lrow[4];
#pragma unroll
    for (int r = 0; r < 4; r++) { mrow[r] = -1e30f; lrow[r] = 0.f; }

    for (int kb = 0; kb <= qb; kb++) {
      __syncthreads();
      {  // stage K tile [kv][d] hi/lo (pre-converted)
#pragma unroll
        for (int i = 0; i < 4; i++) {
          const int row = ksr + i * 16;
          const size_t go = (size_t)(kb * 64 + row) * HD + ksc;
          *(bf16x8*)(&sK[0][row][ksc]) = *(const bf16x8*)(KbH + go);
          *(bf16x8*)(&sK[1][row][ksc]) = *(const bf16x8*)(KbL + go);
        }
      }
      {  // stage V tile [d][kv] hi/lo (pre-transposed)
#pragma unroll
        for (int i = 0; i < 4; i++) {
          const int d = vsd + i * 32;
          const size_t go = (size_t)d * SLEN + kb * 64 + vsk;
          *(bf16x8*)(&sV[0][d][vsk]) = *(const bf16x8*)(VbH + go);
          *(bf16x8*)(&sV[1][d][vsk]) = *(const bf16x8*)(VbL + go);
        }
      }
      __syncthreads();
      f32x4 xs[4];
#pragma unroll
      for (int nt = 0; nt < 4; nt++) {
        f32x4 s = (f32x4){0.f, 0.f, 0.f, 0.f};
        if (kb < qb || nt <= w) {
#pragma unroll
          for (int kc = 0; kc < 4; kc++) {
            bf16x8 kh = *(const bf16x8*)(&sK[0][nt * 16 + m16][kc * 32 + quad * 8]);
            bf16x8 kl = *(const bf16x8*)(&sK[1][nt * 16 + m16][kc * 32 + quad * 8]);
            s = __builtin_amdgcn_mfma_f32_16x16x32_bf16(Qh[kc], kh, s, 0, 0, 0);
            s = __builtin_amdgcn_mfma_f32_16x16x32_bf16(Ql[kc], kh, s, 0, 0, 0);
            s = __builtin_amdgcn_mfma_f32_16x16x32_bf16(Qh[kc], kl, s, 0, 0, 0);
          }
        }
        xs[nt] = s;
      }
      __syncthreads();
      float p[4][4], alpha[4];
#pragma unroll
      for (int r = 0; r < 4; r++) {
        const int rqg = qb * 64 + w * 16 + quad * 4 + r;
        float xr[4];
#pragma unroll
        for (int nt = 0; nt < 4; nt++) {
          int colg = kb * 64 + nt * 16 + m16;
          xr[nt] = (colg <= rqg) ? xs[nt][r] * SCALE : -1e30f;
        }
        float mx = fmaxf(fmaxf(xr[0], xr[1]), fmaxf(xr[2], xr[3]));
#pragma unroll
        for (int off = 1; off < 16; off <<= 1) mx = fmaxf(mx, __shfl_xor(mx, off));
        float mn = fmaxf(mrow[r], mx);
        float al = __expf(mrow[r] - mn);
        float rs = 0.f;
#pragma unroll
        for (int nt = 0; nt < 4; nt++) {
          float pv = __expf(xr[nt] - mn);
          p[nt][r] = pv;
          rs += pv;
        }
#pragma unroll
        for (int off = 1; off < 16; off <<= 1) rs += __shfl_xor(rs, off);
        lrow[r] = lrow[r] * al + rs;
        mrow[r] = mn;
        alpha[r] = al;
      }
#pragma unroll
      for (int dt = 0; dt < 8; dt++)
#pragma unroll
        for (int r = 0; r < 4; r++) acc[dt][r] *= alpha[r];
      {
        bf16_t* base = sP + (size_t)w * 2 * 16 * PSTR;
#pragma unroll
        for (int nt = 0; nt < 4; nt++)
#pragma unroll
          for (int r = 0; r < 4; r++) {
            float pv = p[nt][r];
            bf16_t hi = (bf16_t)pv;
            base[(quad * 4 + r) * PSTR + nt * 16 + m16] = hi;
            base[16 * PSTR + (quad * 4 + r) * PSTR + nt * 16 + m16] = (bf16_t)(pv - (float)hi);
          }
      }
      {
        const bf16_t* base = sP + (size_t)w * 2 * 16 * PSTR;
        bf16x8 Ph[2], Pl[2];
#pragma unroll
        for (int kc = 0; kc < 2; kc++) {
          Ph[kc] = *(const bf16x8*)(base + m16 * PSTR + kc * 32 + quad * 8);
          Pl[kc] = *(const bf16x8*)(base + 16 * PSTR + m16 * PSTR + kc * 32 + quad * 8);
        }
#pragma unroll
        for (int dt = 0; dt < 8; dt++)
#pragma unroll
          for (int kc = 0; kc < 2; kc++) {
            bf16x8 vh = *(const bf16x8*)(&sV[0][dt * 16 + m16][kc * 32 + quad * 8]);
            bf16x8 vl = *(const bf16x8*)(&sV[1][dt * 16 + m16][kc * 32 + quad * 8]);
            acc[dt] = __builtin_amdgcn_mfma_f32_16x16x32_bf16(Ph[kc], vh, acc[dt], 0, 0, 0);
            acc[dt] = __builtin_amdgcn_mfma_f32_16x16x32_bf16(Pl[kc], vh, acc[dt], 0, 0, 0);
            acc[dt] = __builtin_amdgcn_mfma_f32_16x16x32_bf16(Ph[kc], vl, acc[dt], 0, 0, 0);
          }
      }
    }
#pragma unroll
    for (int r = 0; r < 4; r++) {
      const int tok = qb * 64 + w * 16 + quad * 4 + r;
      const float linv = 1.f / lrow[r];
      const size_t ro = (size_t)tok * NQC + hh * HD;
#pragma unroll
      for (int dt = 0; dt < 8; dt++) {
        float v = acc[dt][r] * linv;
        bf16_t hi = (bf16_t)v;
        attnH[ro + dt * 16 + m16] = hi;
        attnL[ro + dt * 16 + m16] = (bf16_t)(v - (float)hi);
      }
    }
  }
}

// ---------------- rmsnorm2 + router logits (fp32, deterministic) ----------------
__global__ __launch_bounds__(256) void rmsnorm2_router_k(const float* __restrict__ hid,
                                                         const float* __restrict__ sc2,
                                                         const float* __restrict__ rW,
                                                         bf16_t* __restrict__ xf,
                                                         float* __restrict__ rlog) {
  const int t = blockIdx.x;
  const float* row = hid + (size_t)t * DMOD;
  const int tid = threadIdx.x;
  const int i0 = tid * 8;
  float4 a = *(const float4*)(row + i0);
  float4 b = *(const float4*)(row + i0 + 4);
  float x[8] = {a.x, a.y, a.z, a.w, b.x, b.y, b.z, b.w};
  float ss = 0.f;
#pragma unroll
  for (int j = 0; j < 8; j++) ss += x[j] * x[j];
  ss = wredsum(ss);
  __shared__ float red[4];
  if ((tid & 63) == 0) red[tid >> 6] = ss;
  __syncthreads();
  float rn = rsqrtf((red[0] + red[1] + red[2] + red[3]) * (1.f / 2048.f) + 1e-6f);
  float acc[8];
#pragma unroll
  for (int e = 0; e < 8; e++) acc[e] = 0.f;
#pragma unroll
  for (int j = 0; j < 8; j++) {
    float xn = x[j] * rn * sc2[i0 + j];
    xf[(size_t)t * DMOD + i0 + j] = (bf16_t)xn;
    const float* w = rW + (size_t)(i0 + j) * NEXP;
#pragma unroll
    for (int e = 0; e < 8; e++) acc[e] += xn * w[e];
  }
#pragma unroll
  for (int e = 0; e < 8; e++) acc[e] = wredsum(acc[e]);
  __shared__ float wacc[4][8];
  if ((tid & 63) == 0)
#pragma unroll
    for (int e = 0; e < 8; e++) wacc[tid >> 6][e] = acc[e];
  __syncthreads();
  if (tid < 8) rlog[t * NEXP + tid] = wacc[0][tid] + wacc[1][tid] + wacc[2][tid] + wacc[3][tid];
}

// ---------------- top-2 selection + gates; aux_loss == 1.0 analytically ----------------
__global__ void topk_k(const float* __restrict__ rlog, int* __restrict__ sel,
                       float* __restrict__ gates, float* __restrict__ aux) {
  int t = blockIdx.x * 256 + threadIdx.x;
  if (t == 0) aux[0] = 1.0f;
  if (t >= SLEN) return;
  const float* l = rlog + t * NEXP;
  int i1 = 0; float v1 = l[0];
#pragma unroll
  for (int e = 1; e < 8; e++) if (l[e] > v1) { v1 = l[e]; i1 = e; }
  int i2 = -1; float v2 = -1e30f;
#pragma unroll
  for (int e = 0; e < 8; e++) if (e != i1 && l[e] > v2) { v2 = l[e]; i2 = e; }
  float e21 = expf(v2 - v1);
  float inv = 1.f / (1.f + e21);
  sel[t * 2 + 0] = i1;
  sel[t * 2 + 1] = i2;
  gates[t * 2 + 0] = inv;
  gates[t * 2 + 1] = e21 * inv;
}

// ---------------- scatter tokens to per-expert lists ----------------
__global__ void scatter_k(const int* __restrict__ sel, const float* __restrict__ gates,
                          int* __restrict__ cnt, int* __restrict__ tok,
                          float* __restrict__ gateL) {
  int i = blockIdx.x * 256 + threadIdx.x;
  if (i >= SLEN * 2) return;
  int e = sel[i];
  int pos = atomicAdd(&cnt[e], 1);
  tok[e * SLEN + pos] = i >> 1;
  gateL[e * SLEN + pos] = gates[i];
}

// ---------------- MoE up-GEMM (gathered rows, silu+bias epilogue, bf16 out) ----------------
__global__ __launch_bounds__(256) void gemm_up_k(const bf16_t* __restrict__ xf,
                                                 const bf16_t* __restrict__ upWT,
                                                 const int* __restrict__ cnt,
                                                 const int* __restrict__ tok,
                                                 const float* __restrict__ up_b,
                                                 bf16_t* __restrict__ hbuf) {
  const int e = blockIdx.z;
  const int c = cnt[e];
  const int m0 = blockIdx.y * 64;
  if (m0 >= c) return;
  const int n0 = blockIdx.x * 64;
  const int* tokE = tok + e * SLEN;
  const bf16_t* BtE = upWT + (size_t)e * NF * DMOD;
  f32x4 zz = {0.f, 0.f, 0.f, 0.f};
  f32x4 acc[4] = {zz, zz, zz, zz};
  gemm_core([=](int r) {
      int s = m0 + r; if (s >= c) s = c - 1;
      return xf + (size_t)tokE[s] * DMOD;
    }, BtE, DMOD, n0, DMOD, acc);
  const int t = threadIdx.x, wave = t >> 6, lane = t & 63;
  const int m16 = lane & 15, quad = lane >> 4;
  const int mb = m0 + wave * 16 + quad * 4;
  const int nb = n0 + m16;
#pragma unroll
  for (int nt = 0; nt < 4; nt++)
#pragma unroll
    for (int r = 0; r < 4; r++) {
      int slot = mb + r;
      if (slot < c) {
        int n = nb + nt * 16;
        float x = acc[nt][r] + up_b[e * NF + n];
        float v = x / (1.f + __expf(-x));
        hbuf[((size_t)e * SLEN + slot) * NF + n] = (bf16_t)v;
      }
    }
}

// ---------------- MoE down-GEMM (bias + gate, atomicAdd into final hidden) ----------------
__global__ __launch_bounds__(256) void gemm_down_k(const bf16_t* __restrict__ hbuf,
                                                   const bf16_t* __restrict__ downWT,
                                                   const int* __restrict__ cnt,
                                                   const int* __restrict__ tok,
                                                   const float* __restrict__ gateL,
                                                   const float* __restrict__ down_b,
                                                   float* __restrict__ outH) {
  const int e = blockIdx.z;
  const int c = cnt[e];
  const int m0 = blockIdx.y * 64;
  if (m0 >= c) return;
  const int n0 = blockIdx.x * 64;
  const bf16_t* Ah = hbuf + (size_t)e * SLEN * NF;
  const bf16_t* BtE = downWT + (size_t)e * DMOD * NF;
  f32x4 zz = {0.f, 0.f, 0.f, 0.f};
  f32x4 acc[4] = {zz, zz, zz, zz};
  gemm_core([=](int r) { return Ah + (size_t)(m0 + r) * NF; }, BtE, NF, n0, NF, acc);
  const int t = threadIdx.x, wave = t >> 6, lane = t & 63;
  const int m16 = lane & 15, quad = lane >> 4;
  const int mb = m0 + wave * 16 + quad * 4;
  const int nb = n0 + m16;
#pragma unroll
  for (int nt = 0; nt < 4; nt++)
#pragma unroll
    for (int r = 0; r < 4; r++) {
      int slot = mb + r;
      if (slot < c) {
        int n = nb + nt * 16;
        int tk = tok[e * SLEN + slot];
        float g = gateL[e * SLEN + slot];
        atomicAdd(&outH[(size_t)tk * DMOD + n], g * (acc[nt][r] + down_b[e * DMOD + n]));
      }
    }
}

// ---------------- host ----------------
extern "C" void kernel_launch(void* const* d_in, const int* in_sizes, int n_in,
                              void* d_out, int out_size, void* d_ws, size_t ws_size,
                              hipStream_t stream) {
  (void)in_sizes; (void)n_in; (void)out_size;
  const float* hs   = (const float*)d_in[0];
  const float* ln1  = (const float*)d_in[1];
  const float* ln2  = (const float*)d_in[2];
  const float* Wq   = (const float*)d_in[3];
  const float* Wk   = (const float*)d_in[4];
  const float* Wv   = (const float*)d_in[5];
  const float* Wo   = (const float*)d_in[6];
  const float* qns  = (const float*)d_in[7];
  const float* kns  = (const float*)d_in[8];
  const float* rW   = (const float*)d_in[9];
  const float* upW  = (const float*)d_in[10];
  const float* upB  = (const float*)d_in[11];
  const float* dnW  = (const float*)d_in[12];
  const float* dnB  = (const float*)d_in[13];
  float* dout = (float*)d_out;

  // ---- workspace layout with lifetime overlays (total ~135.5 MB) ----
  const size_t NEED = 135431168ull;
  if (ws_size < NEED) return;  // clean failure instead of OOB crash
  char* ws = (char*)d_ws;
  const size_t OA = 0;
  const size_t OB = OA + 41943040ull;
  const size_t OC = OB + 33554432ull;
  const size_t OD = OC + 16777216ull;
  const size_t OE = OD + 41943040ull;

  bf16_t* BqkvH  = (bf16_t*)(ws + OA);
  bf16_t* BqkvL  = (bf16_t*)(ws + OA + 20971520ull);
  bf16_t* attnH  = (bf16_t*)(ws + OA);
  bf16_t* attnL  = (bf16_t*)(ws + OA + 16777216ull);
  // K/V pre-pass buffers: live only from kprep/vprep until end of attn;
  // occupy the free tail of OA after Bqkv dies (attnH+attnL = 33.5MB of 41.9MB).
  bf16_t* Kph    = (bf16_t*)(ws + OA + 33554432ull);  // 4*2048*128*2B = 2MB
  bf16_t* Kpl    = Kph + 1048576;
  bf16_t* Vph    = Kpl + 1048576;                     // transposed [hk][d][t]
  bf16_t* Vpl    = Vph + 1048576;
  bf16_t* upWT   = (bf16_t*)(ws + OA);
  bf16_t* WoH    = (bf16_t*)(ws + OB);
  bf16_t* WoL    = (bf16_t*)(ws + OB + 16777216ull);
  bf16_t* hbuf   = (bf16_t*)(ws + OB);
  bf16_t* xnH    = (bf16_t*)(ws + OC);
  bf16_t* xnL    = (bf16_t*)(ws + OC + 8388608ull);
  bf16_t* xf     = (bf16_t*)(ws + OC);
  float*  qkv    = (float*)(ws + OD);
  bf16_t* downWT = (bf16_t*)(ws + OD);
  float*  cosT   = (float*)(ws + OE);
  float*  sinT   = (float*)(ws + OE + 524288ull);
  int*    sel    = (int*)(ws + OE + 1048576ull);
  float*  gates  = (float*)(ws + OE + 1064960ull);
  int*    cnt    = (int*)(ws + OE + 1081344ull);
  int*    tok    = (int*)(ws + OE + 1082368ull);
  float*  gateL  = (float*)(ws + OE + 1147904ull);

  hipMemsetAsync(cnt, 0, 1024, stream);
  rope_table_k<<<512, 256, 0, stream>>>(cosT, sinT);

  dim3 tb(32, 8);
  transpose_split2_k<<<dim3(128, 64), tb, 0, stream>>>(Wq, BqkvH, BqkvL, 2048, 4096);
  transpose_split2_k<<<dim3(16, 64), tb, 0, stream>>>(Wk, BqkvH + (size_t)4096 * 2048,
                                                      BqkvL + (size_t)4096 * 2048, 2048, 512);
  transpose_split2_k<<<dim3(16, 64), tb, 0, stream>>>(Wv, BqkvH + (size_t)4608 * 2048,
                                                      BqkvL + (size_t)4608 * 2048, 2048, 512);
  transpose_split2_k<<<dim3(64, 128), tb, 0, stream>>>(Wo, WoH, WoL, 4096, 2048);

  rmsnorm1_k<<<2048, 256, 0, stream>>>(hs, ln1, xnH, xnL);
  gemm_split128_k<false><<<dim3(40, 16), 256, 0, stream>>>(xnH, xnL, 2048, BqkvH, BqkvL,
                                                           2048, 2048, nullptr, qkv, NQKVC);
  qknorm_rope_k<<<dim3(2048, 36), 128, 0, stream>>>(qkv, qns, kns, cosT, sinT);
  kprep_k<<<512, 256, 0, stream>>>(qkv, Kph, Kpl);
  vprep_k<<<dim3(64, 4, 4), tb, 0, stream>>>(qkv, Vph, Vpl);
  attn_mfma_k<<<dim3(16, 32), 256, 0, stream>>>(qkv, Kph, Kpl, Vph, Vpl, attnH, attnL);
  gemm_split128_k<true><<<dim3(16, 16), 256, 0, stream>>>(attnH, attnL, 4096, WoH, WoL,
                                                          4096, 4096, hs, dout, DMOD);

  rmsnorm2_router_k<<<2048, 256, 0, stream>>>(dout, ln2, rW, xf, dout + 4194304);
  topk_k<<<8, 256, 0, stream>>>(dout + 4194304, sel, gates, dout + 4210688);
  scatter_k<<<16, 256, 0, stream>>>(sel, gates, cnt, tok, gateL);

  transpose_plain_k<<<dim3(24, 64, 8), tb, 0, stream>>>(upW, upWT, 2048, 768);
  transpose_plain_k<<<dim3(64, 24, 8), tb, 0, stream>>>(dnW, downWT, 768, 2048);

  gemm_up_k<<<dim3(12, 32, 8), 256, 0, stream>>>(xf, upWT, cnt, tok, upB, hbuf);
  gemm_down_k<<<dim3(32, 32, 8), 256, 0, stream>>>(hbuf, downWT, cnt, tok, gateL, dnB, dout);
}

// Round 3
// 861.569 us; speedup vs baseline: 1.2952x; 1.0748x over previous
//
#include <hip/hip_runtime.h>
#include <cmath>

typedef __bf16 bf16_t;
typedef __bf16 bf16x8 __attribute__((ext_vector_type(8)));
typedef __bf16 bf16x4 __attribute__((ext_vector_type(4)));
typedef float  f32x4  __attribute__((ext_vector_type(4)));

#define SLEN 2048
#define DMOD 2048
#define NHQ  32
#define NHKV 4
#define HD   128
#define NQC  4096
#define NKVC 512
#define NQKVC 5120
#define NEXP 8
#define NF   768

// LDS strides for attention tiles (inner dim >= full tile extent,
// stride % 8 == 0 for aligned ds_read_b128).
#define KSTR 136
#define VSTR 72
#define PSTR 72

// ---------------- helpers ----------------
__device__ __forceinline__ float wredsum(float v) {
#pragma unroll
  for (int off = 32; off > 0; off >>= 1) v += __shfl_xor(v, off);
  return v;
}

// async global->LDS, 16 B per lane. LDS dest is wave-uniform base + lane*16
// (HW rule) -> pass a wave-uniform LDS pointer; per-lane global pointers.
__device__ __forceinline__ void gll16(const bf16_t* g, bf16_t* l) {
  __builtin_amdgcn_global_load_lds((const __attribute__((address_space(1))) void*)g,
                                   (__attribute__((address_space(3))) void*)l, 16, 0, 0);
}

// ---------------- rope table (fp64 for accuracy) ----------------
__global__ void rope_table_k(float* __restrict__ cosT, float* __restrict__ sinT) {
  int idx = blockIdx.x * 256 + threadIdx.x;
  if (idx >= SLEN * 64) return;
  int t = idx >> 6, j = idx & 63;
  double inv = exp(-0.2158673524681918 * (double)j);  // ln(1e6)/64
  double ang = (double)t * inv;
  cosT[idx] = (float)cos(ang);
  sinT[idx] = (float)sin(ang);
}

// ---------------- weight transpose: fp32 [R][C] -> bf16 hi/lo pair [C][R] ----------------
__global__ __launch_bounds__(256) void transpose_split2_k(const float* __restrict__ in,
                                                          bf16_t* __restrict__ outH,
                                                          bf16_t* __restrict__ outL,
                                                          int R, int C) {
  __shared__ float tile[32][33];
  int tx = threadIdx.x, ty = threadIdx.y;
  int c0 = blockIdx.x * 32, r0 = blockIdx.y * 32;
#pragma unroll
  for (int i = 0; i < 4; i++)
    tile[ty + i * 8][tx] = in[(size_t)(r0 + ty + i * 8) * C + c0 + tx];
  __syncthreads();
#pragma unroll
  for (int i = 0; i < 4; i++) {
    int c = c0 + ty + i * 8;
    int r = r0 + tx;
    float w = tile[tx][ty + i * 8];
    bf16_t hi = (bf16_t)w;
    bf16_t lo = (bf16_t)(w - (float)hi);
    size_t o = (size_t)c * R + r;
    outH[o] = hi;
    outL[o] = lo;
  }
}

// ---------------- plain transpose: fp32 [b][R][C] -> bf16 [b][C][R] ----------------
__global__ __launch_bounds__(256) void transpose_plain_k(const float* __restrict__ in,
                                                         bf16_t* __restrict__ out,
                                                         int R, int C) {
  __shared__ float tile[32][33];
  int b = blockIdx.z;
  const float* inb = in + (size_t)b * R * C;
  bf16_t* outb = out + (size_t)b * R * C;
  int tx = threadIdx.x, ty = threadIdx.y;
  int c0 = blockIdx.x * 32, r0 = blockIdx.y * 32;
#pragma unroll
  for (int i = 0; i < 4; i++)
    tile[ty + i * 8][tx] = inb[(size_t)(r0 + ty + i * 8) * C + c0 + tx];
  __syncthreads();
#pragma unroll
  for (int i = 0; i < 4; i++) {
    int c = c0 + ty + i * 8;
    int r = r0 + tx;
    outb[(size_t)c * R + r] = (bf16_t)tile[tx][ty + i * 8];
  }
}

// ---------------- rmsnorm1: fp32 row -> bf16 hi/lo pair [t][2048] ----------------
__global__ __launch_bounds__(256) void rmsnorm1_k(const float* __restrict__ hs,
                                                  const float* __restrict__ sc,
                                                  bf16_t* __restrict__ xnH,
                                                  bf16_t* __restrict__ xnL) {
  const int t = blockIdx.x;
  const float* row = hs + (size_t)t * DMOD;
  const int tid = threadIdx.x;
  const int i0 = tid * 8;
  float4 a = *(const float4*)(row + i0);
  float4 b = *(const float4*)(row + i0 + 4);
  float x[8] = {a.x, a.y, a.z, a.w, b.x, b.y, b.z, b.w};
  float ss = 0.f;
#pragma unroll
  for (int j = 0; j < 8; j++) ss += x[j] * x[j];
  ss = wredsum(ss);
  __shared__ float red[4];
  if ((tid & 63) == 0) red[tid >> 6] = ss;
  __syncthreads();
  float rn = rsqrtf((red[0] + red[1] + red[2] + red[3]) * (1.f / 2048.f) + 1e-6f);
#pragma unroll
  for (int j = 0; j < 8; j++) {
    float v = x[j] * rn * sc[i0 + j];
    bf16_t hi = (bf16_t)v;
    bf16_t lo = (bf16_t)(v - (float)hi);
    xnH[(size_t)t * DMOD + i0 + j] = hi;
    xnL[(size_t)t * DMOD + i0 + j] = lo;
  }
}

// ---------------- 128x64 split MFMA GEMM, dbuf + counted vmcnt, 3 blocks/CU --------------
// Round-3 change: tile 128x128 -> 128x64 so the double-buffered LDS is 48KB
// -> 3 blocks/CU (was 2 at 64KB; m132 lesson: dbuf that halves residency is a
// wash). Wo grid goes 256 -> 512 blocks (was exactly 1/CU with zero cross-
// block overlap). 4 waves in 2x2: wave quadrant 64x32 = 4x2 MFMA tiles,
// 3 MFMA per fragment pair (hi*hi + lo*hi + hi*lo).
// Staging via global_load_lds width=16, 6 issues per K-step (A hi/lo 2 each,
// B hi/lo 1 each); counted s_waitcnt vmcnt(6) keeps next tile's loads in
// flight across the barrier.
template <bool RESID>
__global__ __launch_bounds__(256, 3) void gemm_split_k(const bf16_t* __restrict__ Ah,
                                                       const bf16_t* __restrict__ Al,
                                                       int lda,
                                                       const bf16_t* __restrict__ Bh,
                                                       const bf16_t* __restrict__ Bl,
                                                       int ldb, int K,
                                                       const float* __restrict__ resid,
                                                       float* __restrict__ C, int ldc) {
  __shared__ bf16_t AsH[2][128][32], AsL[2][128][32], BsH[2][64][32], BsL[2][64][32];
  const int t = threadIdx.x;
  const int w = t >> 6, lane = t & 63;
  const int m16 = lane & 15, quad = lane >> 4;
  // XCD-chunked swizzle (bijective when nwg % 8 == 0; all call sites are).
  const int nwg = gridDim.x * gridDim.y;
  const int flat = blockIdx.y * gridDim.x + blockIdx.x;
  int tile = flat;
  if ((nwg & 7) == 0) tile = (flat & 7) * (nwg >> 3) + (flat >> 3);
  const int bx = tile % gridDim.x, by = tile / gridDim.x;
  const int m0 = by * 128, n0 = bx * 64;
  const int wm = (w & 1) * 64, wn = (w >> 1) * 32;
  f32x4 acc[4][2];
#pragma unroll
  for (int i = 0; i < 4; i++)
#pragma unroll
    for (int j = 0; j < 2; j++) acc[i][j] = (f32x4){0.f, 0.f, 0.f, 0.f};

  const int srow = t >> 2;         // 0..63
  const int scol = (t & 3) * 8;    // element col within BK=32
  const int lw = w * 512;          // wave-uniform LDS elem offset
  const bf16_t* gAh0 = Ah + (size_t)(m0 + srow) * lda + scol;
  const bf16_t* gAh1 = Ah + (size_t)(m0 + 64 + srow) * lda + scol;
  const bf16_t* gAl0 = Al + (size_t)(m0 + srow) * lda + scol;
  const bf16_t* gAl1 = Al + (size_t)(m0 + 64 + srow) * lda + scol;
  const bf16_t* gBh0 = Bh + (size_t)(n0 + srow) * ldb + scol;
  const bf16_t* gBl0 = Bl + (size_t)(n0 + srow) * ldb + scol;

  auto stage = [&](int buf, int k0) {
    gll16(gAh0 + k0, &AsH[buf][0][0] + lw);
    gll16(gAh1 + k0, &AsH[buf][0][0] + 2048 + lw);
    gll16(gAl0 + k0, &AsL[buf][0][0] + lw);
    gll16(gAl1 + k0, &AsL[buf][0][0] + 2048 + lw);
    gll16(gBh0 + k0, &BsH[buf][0][0] + lw);
    gll16(gBl0 + k0, &BsL[buf][0][0] + lw);
  };

  stage(0, 0);
  int cur = 0;
  for (int k0 = 32; k0 <= K; k0 += 32) {
    if (k0 < K) {
      stage(cur ^ 1, k0);
      asm volatile("s_waitcnt vmcnt(6)" ::: "memory");  // wait tile(cur); keep 6 in flight
    } else {
      asm volatile("s_waitcnt vmcnt(0)" ::: "memory");  // final drain
    }
    __builtin_amdgcn_sched_barrier(0);
    __builtin_amdgcn_s_barrier();
    __builtin_amdgcn_sched_barrier(0);
    bf16x8 a_h[4], a_l[4];
#pragma unroll
    for (int mt = 0; mt < 4; mt++) {
      a_h[mt] = *(const bf16x8*)(&AsH[cur][wm + mt * 16 + m16][quad * 8]);
      a_l[mt] = *(const bf16x8*)(&AsL[cur][wm + mt * 16 + m16][quad * 8]);
    }
#pragma unroll
    for (int nt = 0; nt < 2; nt++) {
      bf16x8 b_h = *(const bf16x8*)(&BsH[cur][wn + nt * 16 + m16][quad * 8]);
      bf16x8 b_l = *(const bf16x8*)(&BsL[cur][wn + nt * 16 + m16][quad * 8]);
#pragma unroll
      for (int mt = 0; mt < 4; mt++) {
        acc[mt][nt] = __builtin_amdgcn_mfma_f32_16x16x32_bf16(a_h[mt], b_h, acc[mt][nt], 0, 0, 0);
        acc[mt][nt] = __builtin_amdgcn_mfma_f32_16x16x32_bf16(a_l[mt], b_h, acc[mt][nt], 0, 0, 0);
        acc[mt][nt] = __builtin_amdgcn_mfma_f32_16x16x32_bf16(a_h[mt], b_l, acc[mt][nt], 0, 0, 0);
      }
    }
    // barB: protects buf[cur^1] (read by iter t-1) from next iter's stage.
    __builtin_amdgcn_sched_barrier(0);
    __builtin_amdgcn_s_barrier();
    __builtin_amdgcn_sched_barrier(0);
    cur ^= 1;
  }
  // epilogue: C row = m0+wm+mt*16+quad*4+r, col = n0+wn+nt*16+m16
#pragma unroll
  for (int mt = 0; mt < 4; mt++)
#pragma unroll
    for (int r = 0; r < 4; r++) {
      const size_t row = m0 + wm + mt * 16 + quad * 4 + r;
#pragma unroll
      for (int nt = 0; nt < 2; nt++) {
        const size_t idx = row * ldc + n0 + wn + nt * 16 + m16;
        if (RESID) C[idx] = acc[mt][nt][r] + resid[idx];
        else       C[idx] = acc[mt][nt][r];
      }
    }
}

// ---------------- qk-norm + rope, IN-PLACE on fp32 qkv ----------------
__global__ __launch_bounds__(128) void qknorm_rope_k(float* __restrict__ qkv,
                                                     const float* __restrict__ qsc,
                                                     const float* __restrict__ ksc,
                                                     const float* __restrict__ cosT,
                                                     const float* __restrict__ sinT) {
  const int t = blockIdx.x;
  const int hh = blockIdx.y;  // 0..31 q heads, 32..35 k heads
  const bool isq = hh < NHQ;
  float* ptr = qkv + (size_t)t * NQKVC + (isq ? hh * HD : NQC + (hh - NHQ) * HD);
  const int i = threadIdx.x;
  float x = ptr[i];
  float ss = x * x;
  ss = wredsum(ss);
  __shared__ float red2[2];
  __shared__ float xs[128];
  if ((i & 63) == 0) red2[i >> 6] = ss;
  __syncthreads();
  float rn = rsqrtf((red2[0] + red2[1]) * (1.f / 128.f) + 1e-6f);
  float xn = x * rn * (isq ? qsc[i] : ksc[i]);
  xs[i] = xn;
  __syncthreads();
  int j = i & 63;
  float c = cosT[t * 64 + j];
  float s = sinT[t * 64 + j];
  float rot = (i < 64) ? -xs[i + 64] : xs[i - 64];
  ptr[i] = xn * c + rot * s;
}

// ---------------- K pre-pass: roped fp32 K -> bf16 hi/lo [hk][t][d] ----------------
__global__ __launch_bounds__(256) void kprep_k(const float* __restrict__ qkv,
                                               bf16_t* __restrict__ Kh,
                                               bf16_t* __restrict__ Kl) {
  const int gid = blockIdx.x * 256 + threadIdx.x;  // 131072 threads
  const int tok = gid >> 6;
  const int c = (gid & 63) * 8;  // 0..504 over 4 heads x 128
  const int hk = c >> 7, d = c & 127;
  const float* p = qkv + (size_t)tok * NQKVC + NQC + c;
  float4 a = *(const float4*)p;
  float4 b = *(const float4*)(p + 4);
  float xv[8] = {a.x, a.y, a.z, a.w, b.x, b.y, b.z, b.w};
  bf16x8 hv, lv;
#pragma unroll
  for (int j = 0; j < 8; j++) {
    bf16_t hi = (bf16_t)xv[j];
    hv[j] = hi;
    lv[j] = (bf16_t)(xv[j] - (float)hi);
  }
  const size_t o = ((size_t)hk * SLEN + tok) * HD + d;
  *(bf16x8*)(Kh + o) = hv;
  *(bf16x8*)(Kl + o) = lv;
}

// ---------------- V pre-pass: fp32 V -> bf16 hi/lo TRANSPOSED [hk][d][t] ----------------
__global__ __launch_bounds__(256) void vprep_k(const float* __restrict__ qkv,
                                               bf16_t* __restrict__ Vh,
                                               bf16_t* __restrict__ Vl) {
  __shared__ float tile[32][33];
  const int hk = blockIdx.z;
  const int tx = threadIdx.x, ty = threadIdx.y;
  const int t0 = blockIdx.x * 32, d0 = blockIdx.y * 32;
#pragma unroll
  for (int i = 0; i < 4; i++)
    tile[ty + i * 8][tx] =
        qkv[(size_t)(t0 + ty + i * 8) * NQKVC + NQC + NKVC + hk * HD + d0 + tx];
  __syncthreads();
#pragma unroll
  for (int i = 0; i < 4; i++) {
    int d = d0 + ty + i * 8;
    int tk = t0 + tx;
    float wv = tile[tx][ty + i * 8];
    bf16_t hi = (bf16_t)wv;
    size_t o = ((size_t)hk * HD + d) * SLEN + tk;
    Vh[o] = hi;
    Vl[o] = (bf16_t)(wv - (float)hi);
  }
}

// ---------------- MFMA flash attention, paired 64-row q tiles, full hi/lo split ----------
// Grid (16, 32): block bx handles q-tiles (31-bx) then (bx) -> every block does
// exactly 33 kv-tile iterations; 512 blocks = exactly 2/CU (LDS 70KB) -> one
// perfectly balanced residency wave.
__global__ __launch_bounds__(256) void attn_mfma_k(const float* __restrict__ qkv,
                                                   const bf16_t* __restrict__ Kph,
                                                   const bf16_t* __restrict__ Kpl,
                                                   const bf16_t* __restrict__ Vph,
                                                   const bf16_t* __restrict__ Vpl,
                                                   bf16_t* __restrict__ attnH,
                                                   bf16_t* __restrict__ attnL) {
  const int bx = blockIdx.x;   // 0..15
  const int hh = blockIdx.y;   // q head
  const int hk = hh >> 3;
  __shared__ bf16_t sK[2][64][KSTR];   // [hi/lo][kv=64][d=128]; P overlays after QK^T
  __shared__ bf16_t sV[2][128][VSTR];  // [hi/lo][d=128][kv=64]
  const int t = threadIdx.x;
  const int w = t >> 6, lane = t & 63;
  const int m16 = lane & 15, quad = lane >> 4;
  const float SCALE = 0.08838834764831845f;  // 1/sqrt(128)

  const int ksr = t >> 4;          // 0..15
  const int ksc = (t & 15) * 8;    // 0..120
  const int vsd = t >> 3;          // 0..31
  const int vsk = (t & 7) * 8;     // 0..56
  const bf16_t* KbH = Kph + (size_t)hk * SLEN * HD;
  const bf16_t* KbL = Kpl + (size_t)hk * SLEN * HD;
  const bf16_t* VbH = Vph + (size_t)hk * HD * SLEN;
  const bf16_t* VbL = Vpl + (size_t)hk * HD * SLEN;
  bf16_t* sP = &sK[0][0][0];  // overlay: per-wave [hi/lo][16][PSTR]

  for (int half = 0; half < 2; half++) {
    const int qb = half ? bx : 31 - bx;

    bf16x8 Qh[4], Ql[4];
    {
      const int qrow = qb * 64 + w * 16 + m16;
      const float* qp = qkv + (size_t)qrow * NQKVC + hh * HD + quad * 8;
#pragma unroll
      for (int kc = 0; kc < 4; kc++) {
        float4 x0 = *(const float4*)(qp + kc * 32);
        float4 x1 = *(const float4*)(qp + kc * 32 + 4);
        float xv[8] = {x0.x, x0.y, x0.z, x0.w, x1.x, x1.y, x1.z, x1.w};
#pragma unroll
        for (int j = 0; j < 8; j++) {
          bf16_t hi = (bf16_t)xv[j];
          Qh[kc][j] = hi;
          Ql[kc][j] = (bf16_t)(xv[j] - (float)hi);
        }
      }
    }
    f32x4 acc[8];
#pragma unroll
    for (int i = 0; i < 8; i++) acc[i] = (f32x4){0.f, 0.f, 0.f, 0.f};
    float mrow[4], lrow[4];
#pragma unroll
    for (int r = 0; r < 4; r++) { mrow[r] = -1e30f; lrow[r] = 0.f; }

    for (int kb = 0; kb <= qb; kb++) {
      __syncthreads();
      {  // stage K tile [kv][d] hi/lo (pre-converted)
#pragma unroll
        for (int i = 0; i < 4; i++) {
          const int row = ksr + i * 16;
          const size_t go = (size_t)(kb * 64 + row) * HD + ksc;
          *(bf16x8*)(&sK[0][row][ksc]) = *(const bf16x8*)(KbH + go);
          *(bf16x8*)(&sK[1][row][ksc]) = *(const bf16x8*)(KbL + go);
        }
      }
      {  // stage V tile [d][kv] hi/lo (pre-transposed)
#pragma unroll
        for (int i = 0; i < 4; i++) {
          const int d = vsd + i * 32;
          const size_t go = (size_t)d * SLEN + kb * 64 + vsk;
          *(bf16x8*)(&sV[0][d][vsk]) = *(const bf16x8*)(VbH + go);
          *(bf16x8*)(&sV[1][d][vsk]) = *(const bf16x8*)(VbL + go);
        }
      }
      __syncthreads();
      f32x4 xs[4];
#pragma unroll
      for (int nt = 0; nt < 4; nt++) {
        f32x4 s = (f32x4){0.f, 0.f, 0.f, 0.f};
        if (kb < qb || nt <= w) {
#pragma unroll
          for (int kc = 0; kc < 4; kc++) {
            bf16x8 kh = *(const bf16x8*)(&sK[0][nt * 16 + m16][kc * 32 + quad * 8]);
            bf16x8 kl = *(const bf16x8*)(&sK[1][nt * 16 + m16][kc * 32 + quad * 8]);
            s = __builtin_amdgcn_mfma_f32_16x16x32_bf16(Qh[kc], kh, s, 0, 0, 0);
            s = __builtin_amdgcn_mfma_f32_16x16x32_bf16(Ql[kc], kh, s, 0, 0, 0);
            s = __builtin_amdgcn_mfma_f32_16x16x32_bf16(Qh[kc], kl, s, 0, 0, 0);
          }
        }
        xs[nt] = s;
      }
      __syncthreads();
      float p[4][4], alpha[4];
#pragma unroll
      for (int r = 0; r < 4; r++) {
        const int rqg = qb * 64 + w * 16 + quad * 4 + r;
        float xr[4];
#pragma unroll
        for (int nt = 0; nt < 4; nt++) {
          int colg = kb * 64 + nt * 16 + m16;
          xr[nt] = (colg <= rqg) ? xs[nt][r] * SCALE : -1e30f;
        }
        float mx = fmaxf(fmaxf(xr[0], xr[1]), fmaxf(xr[2], xr[3]));
#pragma unroll
        for (int off = 1; off < 16; off <<= 1) mx = fmaxf(mx, __shfl_xor(mx, off));
        float mn = fmaxf(mrow[r], mx);
        float al = __expf(mrow[r] - mn);
        float rs = 0.f;
#pragma unroll
        for (int nt = 0; nt < 4; nt++) {
          float pv = __expf(xr[nt] - mn);
          p[nt][r] = pv;
          rs += pv;
        }
#pragma unroll
        for (int off = 1; off < 16; off <<= 1) rs += __shfl_xor(rs, off);
        lrow[r] = lrow[r] * al + rs;
        mrow[r] = mn;
        alpha[r] = al;
      }
#pragma unroll
      for (int dt = 0; dt < 8; dt++)
#pragma unroll
        for (int r = 0; r < 4; r++) acc[dt][r] *= alpha[r];
      {
        bf16_t* base = sP + (size_t)w * 2 * 16 * PSTR;
#pragma unroll
        for (int nt = 0; nt < 4; nt++)
#pragma unroll
          for (int r = 0; r < 4; r++) {
            float pv = p[nt][r];
            bf16_t hi = (bf16_t)pv;
            base[(quad * 4 + r) * PSTR + nt * 16 + m16] = hi;
            base[16 * PSTR + (quad * 4 + r) * PSTR + nt * 16 + m16] = (bf16_t)(pv - (float)hi);
          }
      }
      {
        const bf16_t* base = sP + (size_t)w * 2 * 16 * PSTR;
        bf16x8 Ph[2], Pl[2];
#pragma unroll
        for (int kc = 0; kc < 2; kc++) {
          Ph[kc] = *(const bf16x8*)(base + m16 * PSTR + kc * 32 + quad * 8);
          Pl[kc] = *(const bf16x8*)(base + 16 * PSTR + m16 * PSTR + kc * 32 + quad * 8);
        }
#pragma unroll
        for (int dt = 0; dt < 8; dt++)
#pragma unroll
          for (int kc = 0; kc < 2; kc++) {
            bf16x8 vh = *(const bf16x8*)(&sV[0][dt * 16 + m16][kc * 32 + quad * 8]);
            bf16x8 vl = *(const bf16x8*)(&sV[1][dt * 16 + m16][kc * 32 + quad * 8]);
            acc[dt] = __builtin_amdgcn_mfma_f32_16x16x32_bf16(Ph[kc], vh, acc[dt], 0, 0, 0);
            acc[dt] = __builtin_amdgcn_mfma_f32_16x16x32_bf16(Pl[kc], vh, acc[dt], 0, 0, 0);
            acc[dt] = __builtin_amdgcn_mfma_f32_16x16x32_bf16(Ph[kc], vl, acc[dt], 0, 0, 0);
          }
      }
    }
#pragma unroll
    for (int r = 0; r < 4; r++) {
      const int tok = qb * 64 + w * 16 + quad * 4 + r;
      const float linv = 1.f / lrow[r];
      const size_t ro = (size_t)tok * NQC + hh * HD;
#pragma unroll
      for (int dt = 0; dt < 8; dt++) {
        float v = acc[dt][r] * linv;
        bf16_t hi = (bf16_t)v;
        attnH[ro + dt * 16 + m16] = hi;
        attnL[ro + dt * 16 + m16] = (bf16_t)(v - (float)hi);
      }
    }
  }
}

// ---------------- rmsnorm2 + router logits (fp32, deterministic) ----------------
__global__ __launch_bounds__(256) void rmsnorm2_router_k(const float* __restrict__ hid,
                                                         const float* __restrict__ sc2,
                                                         const float* __restrict__ rW,
                                                         bf16_t* __restrict__ xf,
                                                         float* __restrict__ rlog) {
  const int t = blockIdx.x;
  const float* row = hid + (size_t)t * DMOD;
  const int tid = threadIdx.x;
  const int i0 = tid * 8;
  float4 a = *(const float4*)(row + i0);
  float4 b = *(const float4*)(row + i0 + 4);
  float x[8] = {a.x, a.y, a.z, a.w, b.x, b.y, b.z, b.w};
  float ss = 0.f;
#pragma unroll
  for (int j = 0; j < 8; j++) ss += x[j] * x[j];
  ss = wredsum(ss);
  __shared__ float red[4];
  if ((tid & 63) == 0) red[tid >> 6] = ss;
  __syncthreads();
  float rn = rsqrtf((red[0] + red[1] + red[2] + red[3]) * (1.f / 2048.f) + 1e-6f);
  float acc[8];
#pragma unroll
  for (int e = 0; e < 8; e++) acc[e] = 0.f;
#pragma unroll
  for (int j = 0; j < 8; j++) {
    float xn = x[j] * rn * sc2[i0 + j];
    xf[(size_t)t * DMOD + i0 + j] = (bf16_t)xn;
    const float* w = rW + (size_t)(i0 + j) * NEXP;
#pragma unroll
    for (int e = 0; e < 8; e++) acc[e] += xn * w[e];
  }
#pragma unroll
  for (int e = 0; e < 8; e++) acc[e] = wredsum(acc[e]);
  __shared__ float wacc[4][8];
  if ((tid & 63) == 0)
#pragma unroll
    for (int e = 0; e < 8; e++) wacc[tid >> 6][e] = acc[e];
  __syncthreads();
  if (tid < 8) rlog[t * NEXP + tid] = wacc[0][tid] + wacc[1][tid] + wacc[2][tid] + wacc[3][tid];
}

// ---------------- top-2 selection + gates; aux_loss == 1.0 analytically ----------------
__global__ void topk_k(const float* __restrict__ rlog, int* __restrict__ sel,
                       float* __restrict__ gates, float* __restrict__ aux) {
  int t = blockIdx.x * 256 + threadIdx.x;
  if (t == 0) aux[0] = 1.0f;
  if (t >= SLEN) return;
  const float* l = rlog + t * NEXP;
  int i1 = 0; float v1 = l[0];
#pragma unroll
  for (int e = 1; e < 8; e++) if (l[e] > v1) { v1 = l[e]; i1 = e; }
  int i2 = -1; float v2 = -1e30f;
#pragma unroll
  for (int e = 0; e < 8; e++) if (e != i1 && l[e] > v2) { v2 = l[e]; i2 = e; }
  float e21 = expf(v2 - v1);
  float inv = 1.f / (1.f + e21);
  sel[t * 2 + 0] = i1;
  sel[t * 2 + 1] = i2;
  gates[t * 2 + 0] = inv;
  gates[t * 2 + 1] = e21 * inv;
}

// ---------------- scatter tokens to per-expert lists ----------------
__global__ void scatter_k(const int* __restrict__ sel, const float* __restrict__ gates,
                          int* __restrict__ cnt, int* __restrict__ tok,
                          float* __restrict__ gateL) {
  int i = blockIdx.x * 256 + threadIdx.x;
  if (i >= SLEN * 2) return;
  int e = sel[i];
  int pos = atomicAdd(&cnt[e], 1);
  tok[e * SLEN + pos] = i >> 1;
  gateL[e * SLEN + pos] = gates[i];
}

// ---------------- MoE up-GEMM: 128x64 dbuf pipeline, gathered A rows -------------------
// Round-3 change: replaces the naive 64x64 gemm_core (reg-staged LDS + full
// __syncthreads drain each K-step). Same stage->vmcnt(N)->bar->MFMA->bar loop
// as gemm_split_k, single bf16 (1 MFMA per fragment pair), 24KB LDS -> ~5
// blocks/CU. A rows gathered via token list (per-lane global src is allowed).
__global__ __launch_bounds__(256, 5) void gemm_up_k(const bf16_t* __restrict__ xf,
                                                    const bf16_t* __restrict__ upWT,
                                                    const int* __restrict__ cnt,
                                                    const int* __restrict__ tok,
                                                    const float* __restrict__ up_b,
                                                    bf16_t* __restrict__ hbuf) {
  const int e = blockIdx.z;
  const int c = cnt[e];
  const int m0 = blockIdx.y * 128;
  if (m0 >= c) return;
  const int n0 = blockIdx.x * 64;
  __shared__ bf16_t As[2][128][32], Bs[2][64][32];
  const int t = threadIdx.x;
  const int w = t >> 6, lane = t & 63;
  const int m16 = lane & 15, quad = lane >> 4;
  const int wm = (w & 1) * 64, wn = (w >> 1) * 32;
  const int srow = t >> 2, scol = (t & 3) * 8;
  const int lw = w * 512;
  const int* tokE = tok + e * SLEN;
  int r0 = m0 + srow;      if (r0 >= c) r0 = c - 1;
  int r1 = m0 + 64 + srow; if (r1 >= c) r1 = c - 1;
  const bf16_t* ga0 = xf + (size_t)tokE[r0] * DMOD + scol;
  const bf16_t* ga1 = xf + (size_t)tokE[r1] * DMOD + scol;
  const bf16_t* gb0 = upWT + (size_t)e * NF * DMOD + (size_t)(n0 + srow) * DMOD + scol;
  f32x4 acc[4][2];
#pragma unroll
  for (int i = 0; i < 4; i++)
#pragma unroll
    for (int j = 0; j < 2; j++) acc[i][j] = (f32x4){0.f, 0.f, 0.f, 0.f};

  auto stage = [&](int buf, int k0) {
    gll16(ga0 + k0, &As[buf][0][0] + lw);
    gll16(ga1 + k0, &As[buf][0][0] + 2048 + lw);
    gll16(gb0 + k0, &Bs[buf][0][0] + lw);
  };

  stage(0, 0);
  int cur = 0;
  for (int k0 = 32; k0 <= DMOD; k0 += 32) {
    if (k0 < DMOD) {
      stage(cur ^ 1, k0);
      asm volatile("s_waitcnt vmcnt(3)" ::: "memory");
    } else {
      asm volatile("s_waitcnt vmcnt(0)" ::: "memory");
    }
    __builtin_amdgcn_sched_barrier(0);
    __builtin_amdgcn_s_barrier();
    __builtin_amdgcn_sched_barrier(0);
    bf16x8 a[4];
#pragma unroll
    for (int mt = 0; mt < 4; mt++)
      a[mt] = *(const bf16x8*)(&As[cur][wm + mt * 16 + m16][quad * 8]);
#pragma unroll
    for (int nt = 0; nt < 2; nt++) {
      bf16x8 b = *(const bf16x8*)(&Bs[cur][wn + nt * 16 + m16][quad * 8]);
#pragma unroll
      for (int mt = 0; mt < 4; mt++)
        acc[mt][nt] = __builtin_amdgcn_mfma_f32_16x16x32_bf16(a[mt], b, acc[mt][nt], 0, 0, 0);
    }
    __builtin_amdgcn_sched_barrier(0);
    __builtin_amdgcn_s_barrier();
    __builtin_amdgcn_sched_barrier(0);
    cur ^= 1;
  }
#pragma unroll
  for (int mt = 0; mt < 4; mt++)
#pragma unroll
    for (int r = 0; r < 4; r++) {
      int slot = m0 + wm + mt * 16 + quad * 4 + r;
      if (slot < c) {
#pragma unroll
        for (int nt = 0; nt < 2; nt++) {
          int n = n0 + wn + nt * 16 + m16;
          float x = acc[mt][nt][r] + up_b[e * NF + n];
          float v = x / (1.f + __expf(-x));
          hbuf[((size_t)e * SLEN + slot) * NF + n] = (bf16_t)v;
        }
      }
    }
}

// ---------------- MoE down-GEMM: 128x64 dbuf pipeline (bias + gate + atomicAdd) --------
__global__ __launch_bounds__(256, 5) void gemm_down_k(const bf16_t* __restrict__ hbuf,
                                                      const bf16_t* __restrict__ downWT,
                                                      const int* __restrict__ cnt,
                                                      const int* __restrict__ tok,
                                                      const float* __restrict__ gateL,
                                                      const float* __restrict__ down_b,
                                                      float* __restrict__ outH) {
  const int e = blockIdx.z;
  const int c = cnt[e];
  const int m0 = blockIdx.y * 128;
  if (m0 >= c) return;
  const int n0 = blockIdx.x * 64;
  __shared__ bf16_t As[2][128][32], Bs[2][64][32];
  const int t = threadIdx.x;
  const int w = t >> 6, lane = t & 63;
  const int m16 = lane & 15, quad = lane >> 4;
  const int wm = (w & 1) * 64, wn = (w >> 1) * 32;
  const int srow = t >> 2, scol = (t & 3) * 8;
  const int lw = w * 512;
  const bf16_t* Ab = hbuf + (size_t)e * SLEN * NF;
  const bf16_t* ga0 = Ab + (size_t)(m0 + srow) * NF + scol;        // rows < SLEN always valid
  const bf16_t* ga1 = Ab + (size_t)(m0 + 64 + srow) * NF + scol;
  const bf16_t* gb0 = downWT + (size_t)e * DMOD * NF + (size_t)(n0 + srow) * NF + scol;
  f32x4 acc[4][2];
#pragma unroll
  for (int i = 0; i < 4; i++)
#pragma unroll
    for (int j = 0; j < 2; j++) acc[i][j] = (f32x4){0.f, 0.f, 0.f, 0.f};

  auto stage = [&](int buf, int k0) {
    gll16(ga0 + k0, &As[buf][0][0] + lw);
    gll16(ga1 + k0, &As[buf][0][0] + 2048 + lw);
    gll16(gb0 + k0, &Bs[buf][0][0] + lw);
  };

  stage(0, 0);
  int cur = 0;
  for (int k0 = 32; k0 <= NF; k0 += 32) {
    if (k0 < NF) {
      stage(cur ^ 1, k0);
      asm volatile("s_waitcnt vmcnt(3)" ::: "memory");
    } else {
      asm volatile("s_waitcnt vmcnt(0)" ::: "memory");
    }
    __builtin_amdgcn_sched_barrier(0);
    __builtin_amdgcn_s_barrier();
    __builtin_amdgcn_sched_barrier(0);
    bf16x8 a[4];
#pragma unroll
    for (int mt = 0; mt < 4; mt++)
      a[mt] = *(const bf16x8*)(&As[cur][wm + mt * 16 + m16][quad * 8]);
#pragma unroll
    for (int nt = 0; nt < 2; nt++) {
      bf16x8 b = *(const bf16x8*)(&Bs[cur][wn + nt * 16 + m16][quad * 8]);
#pragma unroll
      for (int mt = 0; mt < 4; mt++)
        acc[mt][nt] = __builtin_amdgcn_mfma_f32_16x16x32_bf16(a[mt], b, acc[mt][nt], 0, 0, 0);
    }
    __builtin_amdgcn_sched_barrier(0);
    __builtin_amdgcn_s_barrier();
    __builtin_amdgcn_sched_barrier(0);
    cur ^= 1;
  }
#pragma unroll
  for (int mt = 0; mt < 4; mt++)
#pragma unroll
    for (int r = 0; r < 4; r++) {
      int slot = m0 + wm + mt * 16 + quad * 4 + r;
      if (slot < c) {
        int tk = tok[e * SLEN + slot];
        float g = gateL[e * SLEN + slot];
#pragma unroll
        for (int nt = 0; nt < 2; nt++) {
          int n = n0 + wn + nt * 16 + m16;
          atomicAdd(&outH[(size_t)tk * DMOD + n], g * (acc[mt][nt][r] + down_b[e * DMOD + n]));
        }
      }
    }
}

// ---------------- host ----------------
extern "C" void kernel_launch(void* const* d_in, const int* in_sizes, int n_in,
                              void* d_out, int out_size, void* d_ws, size_t ws_size,
                              hipStream_t stream) {
  (void)in_sizes; (void)n_in; (void)out_size;
  const float* hs   = (const float*)d_in[0];
  const float* ln1  = (const float*)d_in[1];
  const float* ln2  = (const float*)d_in[2];
  const float* Wq   = (const float*)d_in[3];
  const float* Wk   = (const float*)d_in[4];
  const float* Wv   = (const float*)d_in[5];
  const float* Wo   = (const float*)d_in[6];
  const float* qns  = (const float*)d_in[7];
  const float* kns  = (const float*)d_in[8];
  const float* rW   = (const float*)d_in[9];
  const float* upW  = (const float*)d_in[10];
  const float* upB  = (const float*)d_in[11];
  const float* dnW  = (const float*)d_in[12];
  const float* dnB  = (const float*)d_in[13];
  float* dout = (float*)d_out;

  // ---- workspace layout with lifetime overlays (total ~135.5 MB) ----
  const size_t NEED = 135431168ull;
  if (ws_size < NEED) return;  // clean failure instead of OOB crash
  char* ws = (char*)d_ws;
  const size_t OA = 0;
  const size_t OB = OA + 41943040ull;
  const size_t OC = OB + 33554432ull;
  const size_t OD = OC + 16777216ull;
  const size_t OE = OD + 41943040ull;

  bf16_t* BqkvH  = (bf16_t*)(ws + OA);
  bf16_t* BqkvL  = (bf16_t*)(ws + OA + 20971520ull);
  bf16_t* attnH  = (bf16_t*)(ws + OA);
  bf16_t* attnL  = (bf16_t*)(ws + OA + 16777216ull);
  // K/V pre-pass buffers: live only from kprep/vprep until end of attn;
  // occupy the free tail of OA after Bqkv dies (attnH+attnL = 33.5MB of 41.9MB).
  bf16_t* Kph    = (bf16_t*)(ws + OA + 33554432ull);  // 4*2048*128*2B = 2MB
  bf16_t* Kpl    = Kph + 1048576;
  bf16_t* Vph    = Kpl + 1048576;                     // transposed [hk][d][t]
  bf16_t* Vpl    = Vph + 1048576;
  bf16_t* upWT   = (bf16_t*)(ws + OA);
  bf16_t* WoH    = (bf16_t*)(ws + OB);
  bf16_t* WoL    = (bf16_t*)(ws + OB + 16777216ull);
  bf16_t* hbuf   = (bf16_t*)(ws + OB);
  bf16_t* xnH    = (bf16_t*)(ws + OC);
  bf16_t* xnL    = (bf16_t*)(ws + OC + 8388608ull);
  bf16_t* xf     = (bf16_t*)(ws + OC);
  float*  qkv    = (float*)(ws + OD);
  bf16_t* downWT = (bf16_t*)(ws + OD);
  float*  cosT   = (float*)(ws + OE);
  float*  sinT   = (float*)(ws + OE + 524288ull);
  int*    sel    = (int*)(ws + OE + 1048576ull);
  float*  gates  = (float*)(ws + OE + 1064960ull);
  int*    cnt    = (int*)(ws + OE + 1081344ull);
  int*    tok    = (int*)(ws + OE + 1082368ull);
  float*  gateL  = (float*)(ws + OE + 1147904ull);

  hipMemsetAsync(cnt, 0, 1024, stream);
  rope_table_k<<<512, 256, 0, stream>>>(cosT, sinT);

  dim3 tb(32, 8);
  transpose_split2_k<<<dim3(128, 64), tb, 0, stream>>>(Wq, BqkvH, BqkvL, 2048, 4096);
  transpose_split2_k<<<dim3(16, 64), tb, 0, stream>>>(Wk, BqkvH + (size_t)4096 * 2048,
                                                      BqkvL + (size_t)4096 * 2048, 2048, 512);
  transpose_split2_k<<<dim3(16, 64), tb, 0, stream>>>(Wv, BqkvH + (size_t)4608 * 2048,
                                                      BqkvL + (size_t)4608 * 2048, 2048, 512);
  transpose_split2_k<<<dim3(64, 128), tb, 0, stream>>>(Wo, WoH, WoL, 4096, 2048);

  rmsnorm1_k<<<2048, 256, 0, stream>>>(hs, ln1, xnH, xnL);
  gemm_split_k<false><<<dim3(80, 16), 256, 0, stream>>>(xnH, xnL, 2048, BqkvH, BqkvL,
                                                        2048, 2048, nullptr, qkv, NQKVC);
  qknorm_rope_k<<<dim3(2048, 36), 128, 0, stream>>>(qkv, qns, kns, cosT, sinT);
  kprep_k<<<512, 256, 0, stream>>>(qkv, Kph, Kpl);
  vprep_k<<<dim3(64, 4, 4), tb, 0, stream>>>(qkv, Vph, Vpl);
  attn_mfma_k<<<dim3(16, 32), 256, 0, stream>>>(qkv, Kph, Kpl, Vph, Vpl, attnH, attnL);
  gemm_split_k<true><<<dim3(32, 16), 256, 0, stream>>>(attnH, attnL, 4096, WoH, WoL,
                                                       4096, 4096, hs, dout, DMOD);

  rmsnorm2_router_k<<<2048, 256, 0, stream>>>(dout, ln2, rW, xf, dout + 4194304);
  topk_k<<<8, 256, 0, stream>>>(dout + 4194304, sel, gates, dout + 4210688);
  scatter_k<<<16, 256, 0, stream>>>(sel, gates, cnt, tok, gateL);

  transpose_plain_k<<<dim3(24, 64, 8), tb, 0, stream>>>(upW, upWT, 2048, 768);
  transpose_plain_k<<<dim3(64, 24, 8), tb, 0, stream>>>(dnW, downWT, 768, 2048);

  gemm_up_k<<<dim3(12, 16, 8), 256, 0, stream>>>(xf, upWT, cnt, tok, upB, hbuf);
  gemm_down_k<<<dim3(32, 16, 8), 256, 0, stream>>>(hbuf, downWT, cnt, tok, gateL, dnB, dout);
}

// Round 4
// 848.440 us; speedup vs baseline: 1.3152x; 1.0155x over previous
//
#include <hip/hip_runtime.h>
#include <cmath>

typedef __bf16 bf16_t;
typedef __bf16 bf16x8 __attribute__((ext_vector_type(8)));
typedef __bf16 bf16x4 __attribute__((ext_vector_type(4)));
typedef float  f32x4  __attribute__((ext_vector_type(4)));

#define SLEN 2048
#define DMOD 2048
#define NHQ  32
#define NHKV 4
#define HD   128
#define NQC  4096
#define NKVC 512
#define NQKVC 5120
#define NEXP 8
#define NF   768

// LDS strides for attention tiles (inner dim >= full tile extent,
// stride % 8 == 0 for aligned ds_read_b128).
#define KSTR 136
#define VSTR 72
#define PSTR 72

// ---------------- helpers ----------------
__device__ __forceinline__ float wredsum(float v) {
#pragma unroll
  for (int off = 32; off > 0; off >>= 1) v += __shfl_xor(v, off);
  return v;
}

// async global->LDS, 16 B per lane. LDS dest is wave-uniform base + lane*16
// (HW rule) -> pass a wave-uniform LDS pointer; per-lane global pointers.
__device__ __forceinline__ void gll16(const bf16_t* g, bf16_t* l) {
  __builtin_amdgcn_global_load_lds((const __attribute__((address_space(1))) void*)g,
                                   (__attribute__((address_space(3))) void*)l, 16, 0, 0);
}

// ---------------- rope table (fp64 for accuracy) ----------------
__global__ void rope_table_k(float* __restrict__ cosT, float* __restrict__ sinT) {
  int idx = blockIdx.x * 256 + threadIdx.x;
  if (idx >= SLEN * 64) return;
  int t = idx >> 6, j = idx & 63;
  double inv = exp(-0.2158673524681918 * (double)j);  // ln(1e6)/64
  double ang = (double)t * inv;
  cosT[idx] = (float)cos(ang);
  sinT[idx] = (float)sin(ang);
}

// ---------------- weight transpose: fp32 [R][C] -> bf16 hi/lo pair [C][R] ----------------
__global__ __launch_bounds__(256) void transpose_split2_k(const float* __restrict__ in,
                                                          bf16_t* __restrict__ outH,
                                                          bf16_t* __restrict__ outL,
                                                          int R, int C) {
  __shared__ float tile[32][33];
  int tx = threadIdx.x, ty = threadIdx.y;
  int c0 = blockIdx.x * 32, r0 = blockIdx.y * 32;
#pragma unroll
  for (int i = 0; i < 4; i++)
    tile[ty + i * 8][tx] = in[(size_t)(r0 + ty + i * 8) * C + c0 + tx];
  __syncthreads();
#pragma unroll
  for (int i = 0; i < 4; i++) {
    int c = c0 + ty + i * 8;
    int r = r0 + tx;
    float w = tile[tx][ty + i * 8];
    bf16_t hi = (bf16_t)w;
    bf16_t lo = (bf16_t)(w - (float)hi);
    size_t o = (size_t)c * R + r;
    outH[o] = hi;
    outL[o] = lo;
  }
}

// ---------------- plain transpose: fp32 [b][R][C] -> bf16 [b][C][R] ----------------
__global__ __launch_bounds__(256) void transpose_plain_k(const float* __restrict__ in,
                                                         bf16_t* __restrict__ out,
                                                         int R, int C) {
  __shared__ float tile[32][33];
  int b = blockIdx.z;
  const float* inb = in + (size_t)b * R * C;
  bf16_t* outb = out + (size_t)b * R * C;
  int tx = threadIdx.x, ty = threadIdx.y;
  int c0 = blockIdx.x * 32, r0 = blockIdx.y * 32;
#pragma unroll
  for (int i = 0; i < 4; i++)
    tile[ty + i * 8][tx] = inb[(size_t)(r0 + ty + i * 8) * C + c0 + tx];
  __syncthreads();
#pragma unroll
  for (int i = 0; i < 4; i++) {
    int c = c0 + ty + i * 8;
    int r = r0 + tx;
    outb[(size_t)c * R + r] = (bf16_t)tile[tx][ty + i * 8];
  }
}

// ---------------- rmsnorm1: fp32 row -> bf16 hi/lo pair [t][2048] ----------------
__global__ __launch_bounds__(256) void rmsnorm1_k(const float* __restrict__ hs,
                                                  const float* __restrict__ sc,
                                                  bf16_t* __restrict__ xnH,
                                                  bf16_t* __restrict__ xnL) {
  const int t = blockIdx.x;
  const float* row = hs + (size_t)t * DMOD;
  const int tid = threadIdx.x;
  const int i0 = tid * 8;
  float4 a = *(const float4*)(row + i0);
  float4 b = *(const float4*)(row + i0 + 4);
  float x[8] = {a.x, a.y, a.z, a.w, b.x, b.y, b.z, b.w};
  float ss = 0.f;
#pragma unroll
  for (int j = 0; j < 8; j++) ss += x[j] * x[j];
  ss = wredsum(ss);
  __shared__ float red[4];
  if ((tid & 63) == 0) red[tid >> 6] = ss;
  __syncthreads();
  float rn = rsqrtf((red[0] + red[1] + red[2] + red[3]) * (1.f / 2048.f) + 1e-6f);
#pragma unroll
  for (int j = 0; j < 8; j++) {
    float v = x[j] * rn * sc[i0 + j];
    bf16_t hi = (bf16_t)v;
    bf16_t lo = (bf16_t)(v - (float)hi);
    xnH[(size_t)t * DMOD + i0 + j] = hi;
    xnL[(size_t)t * DMOD + i0 + j] = lo;
  }
}

// ---------------- 128x64 split MFMA GEMM, dbuf + counted vmcnt, 3 blocks/CU --------------
template <bool RESID>
__global__ __launch_bounds__(256, 3) void gemm_split_k(const bf16_t* __restrict__ Ah,
                                                       const bf16_t* __restrict__ Al,
                                                       int lda,
                                                       const bf16_t* __restrict__ Bh,
                                                       const bf16_t* __restrict__ Bl,
                                                       int ldb, int K,
                                                       const float* __restrict__ resid,
                                                       float* __restrict__ C, int ldc) {
  __shared__ bf16_t AsH[2][128][32], AsL[2][128][32], BsH[2][64][32], BsL[2][64][32];
  const int t = threadIdx.x;
  const int w = t >> 6, lane = t & 63;
  const int m16 = lane & 15, quad = lane >> 4;
  // XCD-chunked swizzle (bijective when nwg % 8 == 0; all call sites are).
  const int nwg = gridDim.x * gridDim.y;
  const int flat = blockIdx.y * gridDim.x + blockIdx.x;
  int tile = flat;
  if ((nwg & 7) == 0) tile = (flat & 7) * (nwg >> 3) + (flat >> 3);
  const int bx = tile % gridDim.x, by = tile / gridDim.x;
  const int m0 = by * 128, n0 = bx * 64;
  const int wm = (w & 1) * 64, wn = (w >> 1) * 32;
  f32x4 acc[4][2];
#pragma unroll
  for (int i = 0; i < 4; i++)
#pragma unroll
    for (int j = 0; j < 2; j++) acc[i][j] = (f32x4){0.f, 0.f, 0.f, 0.f};

  const int srow = t >> 2;         // 0..63
  const int scol = (t & 3) * 8;    // element col within BK=32
  const int lw = w * 512;          // wave-uniform LDS elem offset
  const bf16_t* gAh0 = Ah + (size_t)(m0 + srow) * lda + scol;
  const bf16_t* gAh1 = Ah + (size_t)(m0 + 64 + srow) * lda + scol;
  const bf16_t* gAl0 = Al + (size_t)(m0 + srow) * lda + scol;
  const bf16_t* gAl1 = Al + (size_t)(m0 + 64 + srow) * lda + scol;
  const bf16_t* gBh0 = Bh + (size_t)(n0 + srow) * ldb + scol;
  const bf16_t* gBl0 = Bl + (size_t)(n0 + srow) * ldb + scol;

  auto stage = [&](int buf, int k0) {
    gll16(gAh0 + k0, &AsH[buf][0][0] + lw);
    gll16(gAh1 + k0, &AsH[buf][0][0] + 2048 + lw);
    gll16(gAl0 + k0, &AsL[buf][0][0] + lw);
    gll16(gAl1 + k0, &AsL[buf][0][0] + 2048 + lw);
    gll16(gBh0 + k0, &BsH[buf][0][0] + lw);
    gll16(gBl0 + k0, &BsL[buf][0][0] + lw);
  };

  stage(0, 0);
  int cur = 0;
  for (int k0 = 32; k0 <= K; k0 += 32) {
    if (k0 < K) {
      stage(cur ^ 1, k0);
      asm volatile("s_waitcnt vmcnt(6)" ::: "memory");  // wait tile(cur); keep 6 in flight
    } else {
      asm volatile("s_waitcnt vmcnt(0)" ::: "memory");  // final drain
    }
    __builtin_amdgcn_sched_barrier(0);
    __builtin_amdgcn_s_barrier();
    __builtin_amdgcn_sched_barrier(0);
    bf16x8 a_h[4], a_l[4];
#pragma unroll
    for (int mt = 0; mt < 4; mt++) {
      a_h[mt] = *(const bf16x8*)(&AsH[cur][wm + mt * 16 + m16][quad * 8]);
      a_l[mt] = *(const bf16x8*)(&AsL[cur][wm + mt * 16 + m16][quad * 8]);
    }
#pragma unroll
    for (int nt = 0; nt < 2; nt++) {
      bf16x8 b_h = *(const bf16x8*)(&BsH[cur][wn + nt * 16 + m16][quad * 8]);
      bf16x8 b_l = *(const bf16x8*)(&BsL[cur][wn + nt * 16 + m16][quad * 8]);
#pragma unroll
      for (int mt = 0; mt < 4; mt++) {
        acc[mt][nt] = __builtin_amdgcn_mfma_f32_16x16x32_bf16(a_h[mt], b_h, acc[mt][nt], 0, 0, 0);
        acc[mt][nt] = __builtin_amdgcn_mfma_f32_16x16x32_bf16(a_l[mt], b_h, acc[mt][nt], 0, 0, 0);
        acc[mt][nt] = __builtin_amdgcn_mfma_f32_16x16x32_bf16(a_h[mt], b_l, acc[mt][nt], 0, 0, 0);
      }
    }
    __builtin_amdgcn_sched_barrier(0);
    __builtin_amdgcn_s_barrier();
    __builtin_amdgcn_sched_barrier(0);
    cur ^= 1;
  }
#pragma unroll
  for (int mt = 0; mt < 4; mt++)
#pragma unroll
    for (int r = 0; r < 4; r++) {
      const size_t row = m0 + wm + mt * 16 + quad * 4 + r;
#pragma unroll
      for (int nt = 0; nt < 2; nt++) {
        const size_t idx = row * ldc + n0 + wn + nt * 16 + m16;
        if (RESID) C[idx] = acc[mt][nt][r] + resid[idx];
        else       C[idx] = acc[mt][nt][r];
      }
    }
}

// ---------------- qk-norm + rope, IN-PLACE on fp32 qkv ----------------
__global__ __launch_bounds__(128) void qknorm_rope_k(float* __restrict__ qkv,
                                                     const float* __restrict__ qsc,
                                                     const float* __restrict__ ksc,
                                                     const float* __restrict__ cosT,
                                                     const float* __restrict__ sinT) {
  const int t = blockIdx.x;
  const int hh = blockIdx.y;  // 0..31 q heads, 32..35 k heads
  const bool isq = hh < NHQ;
  float* ptr = qkv + (size_t)t * NQKVC + (isq ? hh * HD : NQC + (hh - NHQ) * HD);
  const int i = threadIdx.x;
  float x = ptr[i];
  float ss = x * x;
  ss = wredsum(ss);
  __shared__ float red2[2];
  __shared__ float xs[128];
  if ((i & 63) == 0) red2[i >> 6] = ss;
  __syncthreads();
  float rn = rsqrtf((red2[0] + red2[1]) * (1.f / 128.f) + 1e-6f);
  float xn = x * rn * (isq ? qsc[i] : ksc[i]);
  xs[i] = xn;
  __syncthreads();
  int j = i & 63;
  float c = cosT[t * 64 + j];
  float s = sinT[t * 64 + j];
  float rot = (i < 64) ? -xs[i + 64] : xs[i - 64];
  ptr[i] = xn * c + rot * s;
}

// ---------------- K pre-pass: roped fp32 K -> bf16 hi/lo [hk][t][d] ----------------
__global__ __launch_bounds__(256) void kprep_k(const float* __restrict__ qkv,
                                               bf16_t* __restrict__ Kh,
                                               bf16_t* __restrict__ Kl) {
  const int gid = blockIdx.x * 256 + threadIdx.x;  // 131072 threads
  const int tok = gid >> 6;
  const int c = (gid & 63) * 8;  // 0..504 over 4 heads x 128
  const int hk = c >> 7, d = c & 127;
  const float* p = qkv + (size_t)tok * NQKVC + NQC + c;
  float4 a = *(const float4*)p;
  float4 b = *(const float4*)(p + 4);
  float xv[8] = {a.x, a.y, a.z, a.w, b.x, b.y, b.z, b.w};
  bf16x8 hv, lv;
#pragma unroll
  for (int j = 0; j < 8; j++) {
    bf16_t hi = (bf16_t)xv[j];
    hv[j] = hi;
    lv[j] = (bf16_t)(xv[j] - (float)hi);
  }
  const size_t o = ((size_t)hk * SLEN + tok) * HD + d;
  *(bf16x8*)(Kh + o) = hv;
  *(bf16x8*)(Kl + o) = lv;
}

// ---------------- V pre-pass: fp32 V -> bf16 hi/lo TRANSPOSED [hk][d][t] ----------------
__global__ __launch_bounds__(256) void vprep_k(const float* __restrict__ qkv,
                                               bf16_t* __restrict__ Vh,
                                               bf16_t* __restrict__ Vl) {
  __shared__ float tile[32][33];
  const int hk = blockIdx.z;
  const int tx = threadIdx.x, ty = threadIdx.y;
  const int t0 = blockIdx.x * 32, d0 = blockIdx.y * 32;
#pragma unroll
  for (int i = 0; i < 4; i++)
    tile[ty + i * 8][tx] =
        qkv[(size_t)(t0 + ty + i * 8) * NQKVC + NQC + NKVC + hk * HD + d0 + tx];
  __syncthreads();
#pragma unroll
  for (int i = 0; i < 4; i++) {
    int d = d0 + ty + i * 8;
    int tk = t0 + tx;
    float wv = tile[tx][ty + i * 8];
    bf16_t hi = (bf16_t)wv;
    size_t o = ((size_t)hk * HD + d) * SLEN + tk;
    Vh[o] = hi;
    Vl[o] = (bf16_t)(wv - (float)hi);
  }
}

// ---------------- MFMA flash attention, SWAPPED-OPERAND form, hi/lo split ----------------
// Round-4 change: compute S^T = mfma(K, Q) and O^T = mfma(V^T, P) instead of
// mfma(Q,K)/mfma(P,V). All fragment READS are byte-identical to the previous
// (verified) kernel -- only mfma argument order changes. Wins:
//  - lane now holds S^T[kv=nt*16+quad*4+r][q=m16]: kv contiguous per lane ->
//    P-store = 8 aligned b64 stores (was 32 scalar u16 with 4-way collisions)
//  - softmax reduce over kv = 15 in-lane ops + 2 shfl_xor (was 32 ds_swizzles)
//  - running max/denom are per-lane scalars; O-rescale is lane-uniform
//  - output O^T transposed back via per-wave LDS patch once per q-tile
__global__ __launch_bounds__(256) void attn_mfma_k(const float* __restrict__ qkv,
                                                   const bf16_t* __restrict__ Kph,
                                                   const bf16_t* __restrict__ Kpl,
                                                   const bf16_t* __restrict__ Vph,
                                                   const bf16_t* __restrict__ Vpl,
                                                   bf16_t* __restrict__ attnH,
                                                   bf16_t* __restrict__ attnL) {
  const int bx = blockIdx.x;   // 0..15
  const int hh = blockIdx.y;   // q head
  const int hk = hh >> 3;
  __shared__ bf16_t sK[2][64][KSTR];   // [hi/lo][kv=64][d=128]; P + O-transpose overlay
  __shared__ bf16_t sV[2][128][VSTR];  // [hi/lo][d=128][kv=64]
  const int t = threadIdx.x;
  const int w = t >> 6, lane = t & 63;
  const int m16 = lane & 15, quad = lane >> 4;
  const float SCALE = 0.08838834764831845f;  // 1/sqrt(128)

  const int ksr = t >> 4;          // 0..15
  const int ksc = (t & 15) * 8;    // 0..120
  const int vsd = t >> 3;          // 0..31
  const int vsk = (t & 7) * 8;     // 0..56
  const bf16_t* KbH = Kph + (size_t)hk * SLEN * HD;
  const bf16_t* KbL = Kpl + (size_t)hk * SLEN * HD;
  const bf16_t* VbH = Vph + (size_t)hk * HD * SLEN;
  const bf16_t* VbL = Vpl + (size_t)hk * HD * SLEN;
  bf16_t* sP = &sK[0][0][0];  // overlay: per-wave [hi 16 rows + lo 16 rows][PSTR]

  for (int half = 0; half < 2; half++) {
    const int qb = half ? bx : 31 - bx;
    const int qg = qb * 64 + w * 16 + m16;  // this lane's q column (global)

    bf16x8 Qh[4], Ql[4];
    {
      const int qrow = qb * 64 + w * 16 + m16;
      const float* qp = qkv + (size_t)qrow * NQKVC + hh * HD + quad * 8;
#pragma unroll
      for (int kc = 0; kc < 4; kc++) {
        float4 x0 = *(const float4*)(qp + kc * 32);
        float4 x1 = *(const float4*)(qp + kc * 32 + 4);
        float xv[8] = {x0.x, x0.y, x0.z, x0.w, x1.x, x1.y, x1.z, x1.w};
#pragma unroll
        for (int j = 0; j < 8; j++) {
          bf16_t hi = (bf16_t)xv[j];
          Qh[kc][j] = hi;
          Ql[kc][j] = (bf16_t)(xv[j] - (float)hi);
        }
      }
    }
    f32x4 acc[8];  // O^T: acc[dt][r] = O[q=m16][d = dt*16 + quad*4 + r]
#pragma unroll
    for (int i = 0; i < 8; i++) acc[i] = (f32x4){0.f, 0.f, 0.f, 0.f};
    float mrow = -1e30f, lrow = 0.f;

    for (int kb = 0; kb <= qb; kb++) {
      __syncthreads();
      {  // stage K tile [kv][d] hi/lo (pre-converted)
#pragma unroll
        for (int i = 0; i < 4; i++) {
          const int row = ksr + i * 16;
          const size_t go = (size_t)(kb * 64 + row) * HD + ksc;
          *(bf16x8*)(&sK[0][row][ksc]) = *(const bf16x8*)(KbH + go);
          *(bf16x8*)(&sK[1][row][ksc]) = *(const bf16x8*)(KbL + go);
        }
      }
      {  // stage V tile [d][kv] hi/lo (pre-transposed)
#pragma unroll
        for (int i = 0; i < 4; i++) {
          const int d = vsd + i * 32;
          const size_t go = (size_t)d * SLEN + kb * 64 + vsk;
          *(bf16x8*)(&sV[0][d][vsk]) = *(const bf16x8*)(VbH + go);
          *(bf16x8*)(&sV[1][d][vsk]) = *(const bf16x8*)(VbL + go);
        }
      }
      __syncthreads();
      // QK^T swapped: S^T tile = mfma(A=K, B=Q)
      f32x4 xs[4];
#pragma unroll
      for (int nt = 0; nt < 4; nt++) {
        f32x4 s = (f32x4){0.f, 0.f, 0.f, 0.f};
        if (kb < qb || nt <= w) {
#pragma unroll
          for (int kc = 0; kc < 4; kc++) {
            bf16x8 kh = *(const bf16x8*)(&sK[0][nt * 16 + m16][kc * 32 + quad * 8]);
            bf16x8 kl = *(const bf16x8*)(&sK[1][nt * 16 + m16][kc * 32 + quad * 8]);
            s = __builtin_amdgcn_mfma_f32_16x16x32_bf16(kh, Qh[kc], s, 0, 0, 0);
            s = __builtin_amdgcn_mfma_f32_16x16x32_bf16(kh, Ql[kc], s, 0, 0, 0);
            s = __builtin_amdgcn_mfma_f32_16x16x32_bf16(kl, Qh[kc], s, 0, 0, 0);
          }
        }
        xs[nt] = s;
      }
      __syncthreads();
      // softmax: lane owns q column m16; kv values nt*16+quad*4+r in regs
      float xr[4][4], p[4][4];
      float mx = -1e30f;
#pragma unroll
      for (int nt = 0; nt < 4; nt++)
#pragma unroll
        for (int r = 0; r < 4; r++) {
          int kvg = kb * 64 + nt * 16 + quad * 4 + r;
          float v = (kvg <= qg) ? xs[nt][r] * SCALE : -1e30f;
          xr[nt][r] = v;
          mx = fmaxf(mx, v);
        }
      mx = fmaxf(mx, __shfl_xor(mx, 16));
      mx = fmaxf(mx, __shfl_xor(mx, 32));
      float mn = fmaxf(mrow, mx);
      float al = __expf(mrow - mn);
      float rs = 0.f;
#pragma unroll
      for (int nt = 0; nt < 4; nt++)
#pragma unroll
        for (int r = 0; r < 4; r++) {
          float pv = __expf(xr[nt][r] - mn);
          p[nt][r] = pv;
          rs += pv;
        }
      rs += __shfl_xor(rs, 16);
      rs += __shfl_xor(rs, 32);
      lrow = lrow * al + rs;
      mrow = mn;
#pragma unroll
      for (int dt = 0; dt < 8; dt++)
#pragma unroll
        for (int r = 0; r < 4; r++) acc[dt][r] *= al;
      {  // P store, packed: row q=m16, kv = nt*16+quad*4+{0..3} contiguous -> b64
        bf16_t* base = sP + (size_t)w * 2 * 16 * PSTR;
#pragma unroll
        for (int nt = 0; nt < 4; nt++) {
          bf16x4 hv, lv;
#pragma unroll
          for (int r = 0; r < 4; r++) {
            float pv = p[nt][r];
            bf16_t hi = (bf16_t)pv;
            hv[r] = hi;
            lv[r] = (bf16_t)(pv - (float)hi);
          }
          *(bf16x4*)(base + m16 * PSTR + nt * 16 + quad * 4) = hv;
          *(bf16x4*)(base + 16 * PSTR + m16 * PSTR + nt * 16 + quad * 4) = lv;
        }
      }
      {  // PV swapped: O^T += mfma(A=V^T, B=P); reads identical to before
        const bf16_t* base = sP + (size_t)w * 2 * 16 * PSTR;
        bf16x8 Ph[2], Pl[2];
#pragma unroll
        for (int kc = 0; kc < 2; kc++) {
          Ph[kc] = *(const bf16x8*)(base + m16 * PSTR + kc * 32 + quad * 8);
          Pl[kc] = *(const bf16x8*)(base + 16 * PSTR + m16 * PSTR + kc * 32 + quad * 8);
        }
#pragma unroll
        for (int dt = 0; dt < 8; dt++)
#pragma unroll
          for (int kc = 0; kc < 2; kc++) {
            bf16x8 vh = *(const bf16x8*)(&sV[0][dt * 16 + m16][kc * 32 + quad * 8]);
            bf16x8 vl = *(const bf16x8*)(&sV[1][dt * 16 + m16][kc * 32 + quad * 8]);
            acc[dt] = __builtin_amdgcn_mfma_f32_16x16x32_bf16(vh, Ph[kc], acc[dt], 0, 0, 0);
            acc[dt] = __builtin_amdgcn_mfma_f32_16x16x32_bf16(vh, Pl[kc], acc[dt], 0, 0, 0);
            acc[dt] = __builtin_amdgcn_mfma_f32_16x16x32_bf16(vl, Ph[kc], acc[dt], 0, 0, 0);
          }
      }
    }
    // epilogue: O^T (d rows, q cols) -> per-wave LDS patch -> coalesced store
    __syncthreads();
    float* tb = (float*)(&sK[0][0][0]) + (size_t)w * 2048;  // 16 q x 128 d f32
    const float linv = 1.f / lrow;
#pragma unroll
    for (int dt = 0; dt < 8; dt++) {
      f32x4 v = acc[dt];
#pragma unroll
      for (int r = 0; r < 4; r++) v[r] *= linv;
      *(f32x4*)(tb + m16 * 128 + dt * 16 + quad * 4) = v;
    }
    __syncthreads();
    {
      const int qr = lane >> 2, c0 = (lane & 3) * 32;
      const int tok = qb * 64 + w * 16 + qr;
      const size_t ro = (size_t)tok * NQC + hh * HD + c0;
#pragma unroll
      for (int j = 0; j < 4; j++) {
        float4 a = *(const float4*)(tb + qr * 128 + c0 + j * 8);
        float4 b = *(const float4*)(tb + qr * 128 + c0 + j * 8 + 4);
        float xv[8] = {a.x, a.y, a.z, a.w, b.x, b.y, b.z, b.w};
        bf16x8 hv, lv;
#pragma unroll
        for (int jj = 0; jj < 8; jj++) {
          bf16_t hi = (bf16_t)xv[jj];
          hv[jj] = hi;
          lv[jj] = (bf16_t)(xv[jj] - (float)hi);
        }
        *(bf16x8*)(attnH + ro + j * 8) = hv;
        *(bf16x8*)(attnL + ro + j * 8) = lv;
      }
    }
  }
}

// ---------------- rmsnorm2 + router logits (fp32, deterministic) ----------------
__global__ __launch_bounds__(256) void rmsnorm2_router_k(const float* __restrict__ hid,
                                                         const float* __restrict__ sc2,
                                                         const float* __restrict__ rW,
                                                         bf16_t* __restrict__ xf,
                                                         float* __restrict__ rlog) {
  const int t = blockIdx.x;
  const float* row = hid + (size_t)t * DMOD;
  const int tid = threadIdx.x;
  const int i0 = tid * 8;
  float4 a = *(const float4*)(row + i0);
  float4 b = *(const float4*)(row + i0 + 4);
  float x[8] = {a.x, a.y, a.z, a.w, b.x, b.y, b.z, b.w};
  float ss = 0.f;
#pragma unroll
  for (int j = 0; j < 8; j++) ss += x[j] * x[j];
  ss = wredsum(ss);
  __shared__ float red[4];
  if ((tid & 63) == 0) red[tid >> 6] = ss;
  __syncthreads();
  float rn = rsqrtf((red[0] + red[1] + red[2] + red[3]) * (1.f / 2048.f) + 1e-6f);
  float acc[8];
#pragma unroll
  for (int e = 0; e < 8; e++) acc[e] = 0.f;
#pragma unroll
  for (int j = 0; j < 8; j++) {
    float xn = x[j] * rn * sc2[i0 + j];
    xf[(size_t)t * DMOD + i0 + j] = (bf16_t)xn;
    const float* w = rW + (size_t)(i0 + j) * NEXP;
#pragma unroll
    for (int e = 0; e < 8; e++) acc[e] += xn * w[e];
  }
#pragma unroll
  for (int e = 0; e < 8; e++) acc[e] = wredsum(acc[e]);
  __shared__ float wacc[4][8];
  if ((tid & 63) == 0)
#pragma unroll
    for (int e = 0; e < 8; e++) wacc[tid >> 6][e] = acc[e];
  __syncthreads();
  if (tid < 8) rlog[t * NEXP + tid] = wacc[0][tid] + wacc[1][tid] + wacc[2][tid] + wacc[3][tid];
}

// ---------------- top-2 selection + gates; aux_loss == 1.0 analytically ----------------
__global__ void topk_k(const float* __restrict__ rlog, int* __restrict__ sel,
                       float* __restrict__ gates, float* __restrict__ aux) {
  int t = blockIdx.x * 256 + threadIdx.x;
  if (t == 0) aux[0] = 1.0f;
  if (t >= SLEN) return;
  const float* l = rlog + t * NEXP;
  int i1 = 0; float v1 = l[0];
#pragma unroll
  for (int e = 1; e < 8; e++) if (l[e] > v1) { v1 = l[e]; i1 = e; }
  int i2 = -1; float v2 = -1e30f;
#pragma unroll
  for (int e = 0; e < 8; e++) if (e != i1 && l[e] > v2) { v2 = l[e]; i2 = e; }
  float e21 = expf(v2 - v1);
  float inv = 1.f / (1.f + e21);
  sel[t * 2 + 0] = i1;
  sel[t * 2 + 1] = i2;
  gates[t * 2 + 0] = inv;
  gates[t * 2 + 1] = e21 * inv;
}

// ---------------- scatter tokens to per-expert lists (+ inverse position map) ----------
__global__ void scatter_k(const int* __restrict__ sel, const float* __restrict__ gates,
                          int* __restrict__ cnt, int* __restrict__ tok,
                          float* __restrict__ gateL, int* __restrict__ posOf) {
  int i = blockIdx.x * 256 + threadIdx.x;
  if (i >= SLEN * 2) return;
  int e = sel[i];
  int pos = atomicAdd(&cnt[e], 1);
  tok[e * SLEN + pos] = i >> 1;
  gateL[e * SLEN + pos] = gates[i];
  posOf[i] = pos;
}

// ---------------- expert base prefix (8 values, 1 thread) ----------------
__global__ void prefix_k(const int* __restrict__ cnt, int* __restrict__ baseP) {
  if (threadIdx.x == 0) {
    int b = 0;
#pragma unroll
    for (int e = 0; e < 8; e++) { baseP[e] = b; b += cnt[e]; }
  }
}

// ---------------- MoE up-GEMM: 128x64 dbuf pipeline, gathered A rows -------------------
__global__ __launch_bounds__(256, 5) void gemm_up_k(const bf16_t* __restrict__ xf,
                                                    const bf16_t* __restrict__ upWT,
                                                    const int* __restrict__ cnt,
                                                    const int* __restrict__ tok,
                                                    const float* __restrict__ up_b,
                                                    bf16_t* __restrict__ hbuf) {
  const int e = blockIdx.z;
  const int c = cnt[e];
  const int m0 = blockIdx.y * 128;
  if (m0 >= c) return;
  const int n0 = blockIdx.x * 64;
  __shared__ bf16_t As[2][128][32], Bs[2][64][32];
  const int t = threadIdx.x;
  const int w = t >> 6, lane = t & 63;
  const int m16 = lane & 15, quad = lane >> 4;
  const int wm = (w & 1) * 64, wn = (w >> 1) * 32;
  const int srow = t >> 2, scol = (t & 3) * 8;
  const int lw = w * 512;
  const int* tokE = tok + e * SLEN;
  int r0 = m0 + srow;      if (r0 >= c) r0 = c - 1;
  int r1 = m0 + 64 + srow; if (r1 >= c) r1 = c - 1;
  const bf16_t* ga0 = xf + (size_t)tokE[r0] * DMOD + scol;
  const bf16_t* ga1 = xf + (size_t)tokE[r1] * DMOD + scol;
  const bf16_t* gb0 = upWT + (size_t)e * NF * DMOD + (size_t)(n0 + srow) * DMOD + scol;
  f32x4 acc[4][2];
#pragma unroll
  for (int i = 0; i < 4; i++)
#pragma unroll
    for (int j = 0; j < 2; j++) acc[i][j] = (f32x4){0.f, 0.f, 0.f, 0.f};

  auto stage = [&](int buf, int k0) {
    gll16(ga0 + k0, &As[buf][0][0] + lw);
    gll16(ga1 + k0, &As[buf][0][0] + 2048 + lw);
    gll16(gb0 + k0, &Bs[buf][0][0] + lw);
  };

  stage(0, 0);
  int cur = 0;
  for (int k0 = 32; k0 <= DMOD; k0 += 32) {
    if (k0 < DMOD) {
      stage(cur ^ 1, k0);
      asm volatile("s_waitcnt vmcnt(3)" ::: "memory");
    } else {
      asm volatile("s_waitcnt vmcnt(0)" ::: "memory");
    }
    __builtin_amdgcn_sched_barrier(0);
    __builtin_amdgcn_s_barrier();
    __builtin_amdgcn_sched_barrier(0);
    bf16x8 a[4];
#pragma unroll
    for (int mt = 0; mt < 4; mt++)
      a[mt] = *(const bf16x8*)(&As[cur][wm + mt * 16 + m16][quad * 8]);
#pragma unroll
    for (int nt = 0; nt < 2; nt++) {
      bf16x8 b = *(const bf16x8*)(&Bs[cur][wn + nt * 16 + m16][quad * 8]);
#pragma unroll
      for (int mt = 0; mt < 4; mt++)
        acc[mt][nt] = __builtin_amdgcn_mfma_f32_16x16x32_bf16(a[mt], b, acc[mt][nt], 0, 0, 0);
    }
    __builtin_amdgcn_sched_barrier(0);
    __builtin_amdgcn_s_barrier();
    __builtin_amdgcn_sched_barrier(0);
    cur ^= 1;
  }
#pragma unroll
  for (int mt = 0; mt < 4; mt++)
#pragma unroll
    for (int r = 0; r < 4; r++) {
      int slot = m0 + wm + mt * 16 + quad * 4 + r;
      if (slot < c) {
#pragma unroll
        for (int nt = 0; nt < 2; nt++) {
          int n = n0 + wn + nt * 16 + m16;
          float x = acc[mt][nt][r] + up_b[e * NF + n];
          float v = x / (1.f + __expf(-x));
          hbuf[((size_t)e * SLEN + slot) * NF + n] = (bf16_t)v;
        }
      }
    }
}

// ---------------- MoE down-GEMM: 128x64 dbuf pipeline -> dense f32 dbuf (no atomics) ---
__global__ __launch_bounds__(256, 5) void gemm_down_k(const bf16_t* __restrict__ hbuf,
                                                      const bf16_t* __restrict__ downWT,
                                                      const int* __restrict__ cnt,
                                                      const float* __restrict__ gateL,
                                                      const float* __restrict__ down_b,
                                                      const int* __restrict__ baseP,
                                                      float* __restrict__ dbuf) {
  const int e = blockIdx.z;
  const int c = cnt[e];
  const int m0 = blockIdx.y * 128;
  if (m0 >= c) return;
  const int n0 = blockIdx.x * 64;
  __shared__ bf16_t As[2][128][32], Bs[2][64][32];
  const int t = threadIdx.x;
  const int w = t >> 6, lane = t & 63;
  const int m16 = lane & 15, quad = lane >> 4;
  const int wm = (w & 1) * 64, wn = (w >> 1) * 32;
  const int srow = t >> 2, scol = (t & 3) * 8;
  const int lw = w * 512;
  const bf16_t* Ab = hbuf + (size_t)e * SLEN * NF;
  const bf16_t* ga0 = Ab + (size_t)(m0 + srow) * NF + scol;
  const bf16_t* ga1 = Ab + (size_t)(m0 + 64 + srow) * NF + scol;
  const bf16_t* gb0 = downWT + (size_t)e * DMOD * NF + (size_t)(n0 + srow) * NF + scol;
  f32x4 acc[4][2];
#pragma unroll
  for (int i = 0; i < 4; i++)
#pragma unroll
    for (int j = 0; j < 2; j++) acc[i][j] = (f32x4){0.f, 0.f, 0.f, 0.f};

  auto stage = [&](int buf, int k0) {
    gll16(ga0 + k0, &As[buf][0][0] + lw);
    gll16(ga1 + k0, &As[buf][0][0] + 2048 + lw);
    gll16(gb0 + k0, &Bs[buf][0][0] + lw);
  };

  stage(0, 0);
  int cur = 0;
  for (int k0 = 32; k0 <= NF; k0 += 32) {
    if (k0 < NF) {
      stage(cur ^ 1, k0);
      asm volatile("s_waitcnt vmcnt(3)" ::: "memory");
    } else {
      asm volatile("s_waitcnt vmcnt(0)" ::: "memory");
    }
    __builtin_amdgcn_sched_barrier(0);
    __builtin_amdgcn_s_barrier();
    __builtin_amdgcn_sched_barrier(0);
    bf16x8 a[4];
#pragma unroll
    for (int mt = 0; mt < 4; mt++)
      a[mt] = *(const bf16x8*)(&As[cur][wm + mt * 16 + m16][quad * 8]);
#pragma unroll
    for (int nt = 0; nt < 2; nt++) {
      bf16x8 b = *(const bf16x8*)(&Bs[cur][wn + nt * 16 + m16][quad * 8]);
#pragma unroll
      for (int mt = 0; mt < 4; mt++)
        acc[mt][nt] = __builtin_amdgcn_mfma_f32_16x16x32_bf16(a[mt], b, acc[mt][nt], 0, 0, 0);
    }
    __builtin_amdgcn_sched_barrier(0);
    __builtin_amdgcn_s_barrier();
    __builtin_amdgcn_sched_barrier(0);
    cur ^= 1;
  }
  const int eb = baseP[e];
#pragma unroll
  for (int mt = 0; mt < 4; mt++)
#pragma unroll
    for (int r = 0; r < 4; r++) {
      int slot = m0 + wm + mt * 16 + quad * 4 + r;
      if (slot < c) {
        float g = gateL[e * SLEN + slot];
#pragma unroll
        for (int nt = 0; nt < 2; nt++) {
          int n = n0 + wn + nt * 16 + m16;
          dbuf[(size_t)(eb + slot) * DMOD + n] = g * (acc[mt][nt][r] + down_b[e * DMOD + n]);
        }
      }
    }
}

// ---------------- combine: dout += gated expert rows (replaces atomics) ----------------
__global__ __launch_bounds__(256) void combine_k(const float* __restrict__ dbuf,
                                                 const int* __restrict__ sel,
                                                 const int* __restrict__ posOf,
                                                 const int* __restrict__ baseP,
                                                 float* __restrict__ dout) {
  const int t = blockIdx.x;
  const int i0 = threadIdx.x * 8;
  const int r0 = baseP[sel[t * 2 + 0]] + posOf[t * 2 + 0];
  const int r1 = baseP[sel[t * 2 + 1]] + posOf[t * 2 + 1];
  const float* a = dbuf + (size_t)r0 * DMOD + i0;
  const float* b = dbuf + (size_t)r1 * DMOD + i0;
  float* o = dout + (size_t)t * DMOD + i0;
  float4 o0 = *(const float4*)o,       o1 = *(const float4*)(o + 4);
  float4 a0 = *(const float4*)a,       a1 = *(const float4*)(a + 4);
  float4 b0 = *(const float4*)b,       b1 = *(const float4*)(b + 4);
  o0.x += a0.x + b0.x; o0.y += a0.y + b0.y; o0.z += a0.z + b0.z; o0.w += a0.w + b0.w;
  o1.x += a1.x + b1.x; o1.y += a1.y + b1.y; o1.z += a1.z + b1.z; o1.w += a1.w + b1.w;
  *(float4*)o = o0;
  *(float4*)(o + 4) = o1;
}

// ---------------- host ----------------
extern "C" void kernel_launch(void* const* d_in, const int* in_sizes, int n_in,
                              void* d_out, int out_size, void* d_ws, size_t ws_size,
                              hipStream_t stream) {
  (void)in_sizes; (void)n_in; (void)out_size;
  const float* hs   = (const float*)d_in[0];
  const float* ln1  = (const float*)d_in[1];
  const float* ln2  = (const float*)d_in[2];
  const float* Wq   = (const float*)d_in[3];
  const float* Wk   = (const float*)d_in[4];
  const float* Wv   = (const float*)d_in[5];
  const float* Wo   = (const float*)d_in[6];
  const float* qns  = (const float*)d_in[7];
  const float* kns  = (const float*)d_in[8];
  const float* rW   = (const float*)d_in[9];
  const float* upW  = (const float*)d_in[10];
  const float* upB  = (const float*)d_in[11];
  const float* dnW  = (const float*)d_in[12];
  const float* dnB  = (const float*)d_in[13];
  float* dout = (float*)d_out;

  // ---- workspace layout with lifetime overlays (total ~135.5 MB) ----
  const size_t NEED = 135431168ull;
  if (ws_size < NEED) return;  // clean failure instead of OOB crash
  char* ws = (char*)d_ws;
  const size_t OA = 0;
  const size_t OB = OA + 41943040ull;
  const size_t OC = OB + 33554432ull;
  const size_t OD = OC + 16777216ull;
  const size_t OE = OD + 41943040ull;

  bf16_t* BqkvH  = (bf16_t*)(ws + OA);
  bf16_t* BqkvL  = (bf16_t*)(ws + OA + 20971520ull);
  bf16_t* attnH  = (bf16_t*)(ws + OA);
  bf16_t* attnL  = (bf16_t*)(ws + OA + 16777216ull);
  bf16_t* Kph    = (bf16_t*)(ws + OA + 33554432ull);  // 4*2048*128*2B = 2MB
  bf16_t* Kpl    = Kph + 1048576;
  bf16_t* Vph    = Kpl + 1048576;                     // transposed [hk][d][t]
  bf16_t* Vpl    = Vph + 1048576;
  bf16_t* upWT   = (bf16_t*)(ws + OA);
  float*  dbuf   = (float*)(ws + OA);   // MoE phase: 4096x2048 f32 = 32MB (OA dead then)
  bf16_t* WoH    = (bf16_t*)(ws + OB);
  bf16_t* WoL    = (bf16_t*)(ws + OB + 16777216ull);
  bf16_t* hbuf   = (bf16_t*)(ws + OB);
  bf16_t* xnH    = (bf16_t*)(ws + OC);
  bf16_t* xnL    = (bf16_t*)(ws + OC + 8388608ull);
  bf16_t* xf     = (bf16_t*)(ws + OC);
  float*  qkv    = (float*)(ws + OD);
  bf16_t* downWT = (bf16_t*)(ws + OD);
  float*  cosT   = (float*)(ws + OE);
  float*  sinT   = (float*)(ws + OE + 524288ull);
  int*    sel    = (int*)(ws + OE + 1048576ull);
  float*  gates  = (float*)(ws + OE + 1064960ull);
  int*    cnt    = (int*)(ws + OE + 1081344ull);
  int*    tok    = (int*)(ws + OE + 1082368ull);
  float*  gateL  = (float*)(ws + OE + 1147904ull);
  int*    posOf  = (int*)(ws + OE + 1213440ull);   // 4096 ints
  int*    baseP  = (int*)(ws + OE + 1229824ull);   // 8 ints

  hipMemsetAsync(cnt, 0, 1024, stream);
  rope_table_k<<<512, 256, 0, stream>>>(cosT, sinT);

  dim3 tb(32, 8);
  transpose_split2_k<<<dim3(128, 64), tb, 0, stream>>>(Wq, BqkvH, BqkvL, 2048, 4096);
  transpose_split2_k<<<dim3(16, 64), tb, 0, stream>>>(Wk, BqkvH + (size_t)4096 * 2048,
                                                      BqkvL + (size_t)4096 * 2048, 2048, 512);
  transpose_split2_k<<<dim3(16, 64), tb, 0, stream>>>(Wv, BqkvH + (size_t)4608 * 2048,
                                                      BqkvL + (size_t)4608 * 2048, 2048, 512);
  transpose_split2_k<<<dim3(64, 128), tb, 0, stream>>>(Wo, WoH, WoL, 4096, 2048);

  rmsnorm1_k<<<2048, 256, 0, stream>>>(hs, ln1, xnH, xnL);
  gemm_split_k<false><<<dim3(80, 16), 256, 0, stream>>>(xnH, xnL, 2048, BqkvH, BqkvL,
                                                        2048, 2048, nullptr, qkv, NQKVC);
  qknorm_rope_k<<<dim3(2048, 36), 128, 0, stream>>>(qkv, qns, kns, cosT, sinT);
  kprep_k<<<512, 256, 0, stream>>>(qkv, Kph, Kpl);
  vprep_k<<<dim3(64, 4, 4), tb, 0, stream>>>(qkv, Vph, Vpl);
  attn_mfma_k<<<dim3(16, 32), 256, 0, stream>>>(qkv, Kph, Kpl, Vph, Vpl, attnH, attnL);
  gemm_split_k<true><<<dim3(32, 16), 256, 0, stream>>>(attnH, attnL, 4096, WoH, WoL,
                                                       4096, 4096, hs, dout, DMOD);

  rmsnorm2_router_k<<<2048, 256, 0, stream>>>(dout, ln2, rW, xf, dout + 4194304);
  topk_k<<<8, 256, 0, stream>>>(dout + 4194304, sel, gates, dout + 4210688);
  scatter_k<<<16, 256, 0, stream>>>(sel, gates, cnt, tok, gateL, posOf);
  prefix_k<<<1, 64, 0, stream>>>(cnt, baseP);

  transpose_plain_k<<<dim3(24, 64, 8), tb, 0, stream>>>(upW, upWT, 2048, 768);
  transpose_plain_k<<<dim3(64, 24, 8), tb, 0, stream>>>(dnW, downWT, 768, 2048);

  gemm_up_k<<<dim3(12, 16, 8), 256, 0, stream>>>(xf, upWT, cnt, tok, upB, hbuf);
  gemm_down_k<<<dim3(32, 16, 8), 256, 0, stream>>>(hbuf, downWT, cnt, gateL, dnB, baseP, dbuf);
  combine_k<<<2048, 256, 0, stream>>>(dbuf, sel, posOf, baseP, dout);
}